// Round 9
// baseline (300.255 us; speedup 1.0000x reference)
//
#include <hip/hip_runtime.h>
#include <hip/hip_bf16.h>
#include <cstdint>
#include <cstddef>

typedef __bf16 bf16_t;
typedef __bf16 bf16x8 __attribute__((ext_vector_type(8)));
typedef float f32x4 __attribute__((ext_vector_type(4)));

static __device__ __forceinline__ void st_out(float* p, float v) { *p = v; }
static __device__ __forceinline__ void st_out(bf16_t* p, float v) { *p = (bf16_t)v; }

static __device__ __forceinline__ void async_cp16(const bf16_t* g, bf16_t* l) {
  __builtin_amdgcn_global_load_lds(
      (const __attribute__((address_space(1))) void*)g,
      (__attribute__((address_space(3))) void*)l, 16, 0, 0);
}

// =====================================================================
// prep: all setup work in ONE launch. 1D grid, block ranges:
// [0,2048) cvt hs | [2048,6144) W transposes | [6144,6400) ta^T
// [6400,6656) tb^T | [6656,6668) bias concat | [6668,6684) low bias
// =====================================================================
__global__ __launch_bounds__(256) void prep(const float* __restrict__ hs, bf16_t* __restrict__ hsb,
                                            const float* __restrict__ Wq, const float* __restrict__ Wk,
                                            const float* __restrict__ Wv, const float* __restrict__ Wo,
                                            bf16_t* __restrict__ BtExt, bf16_t* __restrict__ WoT,
                                            bf16_t* __restrict__ Wqb, bf16_t* __restrict__ Wkb,
                                            const float* __restrict__ qta, const float* __restrict__ kta,
                                            bf16_t* __restrict__ qtaT, bf16_t* __restrict__ ktaT,
                                            const float* __restrict__ qtb, const float* __restrict__ ktb,
                                            bf16_t* __restrict__ qtbT, bf16_t* __restrict__ ktbT,
                                            const float* __restrict__ bq, const float* __restrict__ bk,
                                            const float* __restrict__ bv, float* __restrict__ biasN) {
  __shared__ float tile[32][33];
  const int bid = blockIdx.x, t = threadIdx.x;
  const int tx = t & 31, ty = t >> 5;

  if (bid < 2048) {  // ---- cvt ----
    int i = (bid * 256 + t) * 8;
    float4 a = *(const float4*)(hs + i);
    float4 b = *(const float4*)(hs + i + 4);
    union { bf16_t h[8]; uint4 u; } p;
    p.h[0] = (bf16_t)a.x; p.h[1] = (bf16_t)a.y; p.h[2] = (bf16_t)a.z; p.h[3] = (bf16_t)a.w;
    p.h[4] = (bf16_t)b.x; p.h[5] = (bf16_t)b.y; p.h[6] = (bf16_t)b.z; p.h[7] = (bf16_t)b.w;
    *(uint4*)(hsb + i) = p.u;
  } else if (bid < 6144) {  // ---- weight transposes ----
    int r = bid - 2048, z = r >> 10, r10 = r & 1023;
    int bx = (r10 & 31) * 32, by = (r10 >> 5) * 32;
    const float* src = z == 0 ? Wq : z == 1 ? Wk : z == 2 ? Wv : Wo;
    bf16_t* dst = z == 3 ? WoT : BtExt + (size_t)z * 1048576;
    bf16_t* sd = z == 0 ? Wqb : z == 1 ? Wkb : nullptr;
#pragma unroll
    for (int i = 0; i < 4; ++i) {
      float v = src[(size_t)(by + ty + i * 8) * 1024 + bx + tx];
      tile[ty + i * 8][tx] = v;
      if (sd) sd[(size_t)(by + ty + i * 8) * 1024 + bx + tx] = (bf16_t)v;
    }
    __syncthreads();
#pragma unroll
    for (int i = 0; i < 4; ++i)
      dst[(size_t)(bx + ty + i * 8) * 1024 + by + tx] = (bf16_t)tile[tx][ty + i * 8];
  } else if (bid < 6400) {  // ---- ta: [1024][64] -> [64][1024] ----
    int r = bid - 6144, z = r >> 6, r6 = r & 63;
    int bx = (r6 & 1) * 32, by = (r6 >> 1) * 32;
    const float* src = ((z >> 1) ? kta : qta) + (size_t)(z & 1) * 65536;
    bf16_t* dst = ((z >> 1) ? ktaT : qtaT) + (size_t)(z & 1) * 65536;
#pragma unroll
    for (int i = 0; i < 4; ++i)
      tile[ty + i * 8][tx] = src[(size_t)(by + ty + i * 8) * 64 + bx + tx];
    __syncthreads();
#pragma unroll
    for (int i = 0; i < 4; ++i)
      dst[(size_t)(bx + ty + i * 8) * 1024 + by + tx] = (bf16_t)tile[tx][ty + i * 8];
  } else if (bid < 6656) {  // ---- tb: [64][1024] -> [1024][64] ----
    int r = bid - 6400, z = r >> 6, r6 = r & 63;
    int bx = (r6 & 31) * 32, by = (r6 >> 5) * 32;
    const float* src = ((z >> 1) ? ktb : qtb) + (size_t)(z & 1) * 65536;
    bf16_t* dst = ((z >> 1) ? ktbT : qtbT) + (size_t)(z & 1) * 65536;
#pragma unroll
    for (int i = 0; i < 4; ++i)
      tile[ty + i * 8][tx] = src[(size_t)(by + ty + i * 8) * 1024 + bx + tx];
    __syncthreads();
#pragma unroll
    for (int i = 0; i < 4; ++i)
      dst[(size_t)(bx + ty + i * 8) * 64 + by + tx] = (bf16_t)tile[tx][ty + i * 8];
  } else if (bid < 6668) {  // ---- bias concat ----
    int i = (bid - 6656) * 256 + t;
    biasN[i] = (i < 1024) ? bq[i] : (i < 2048 ? bk[i - 1024] : bv[i - 2048]);
  } else {  // ---- low bias: 16 blocks x 16 j-outputs, 16 h-lanes each ----
    int B = bid - 6668;                 // 0..15
    int j = B * 16 + (t >> 4);          // output index 0..255
    int hoff = t & 15;
    const float* b = (j < 128) ? bq : bk;
    const float* ta = ((j < 128) ? qta : kta) + (size_t)((j >> 6) & 1) * 65536;
    int rr = j & 63;
    float s = 0.f;
#pragma unroll 4
    for (int i = 0; i < 64; ++i) {
      int h = hoff + i * 16;
      s += b[h] * ta[(size_t)h * 64 + rr];
    }
    // reduce across the 16 h-lanes (xor widths 1,2,4,8 stay in-wave)
#pragma unroll
    for (int m = 8; m >= 1; m >>= 1) s += __shfl_xor(s, m, 64);
    if (hoff == 0) biasN[3072 + j] = s;
  }
}

// =====================================================================
// 128x128 BK=64 async GEMM core: m97 fragment layout, 64-wide K-steps
// (half the barrier pairs). Bank swizzle via pre-swizzled global SOURCE
// + swizzled read (rule #21), chunk ^= row&7; DMA dest stays linear.
// =====================================================================
template <typename OutT>
static __device__ __forceinline__ void gemm_core_bk64(const bf16_t* __restrict__ A, int lda,
                                                      const bf16_t* __restrict__ Bt, int ldb,
                                                      OutT* __restrict__ C, int ldc,
                                                      const float* __restrict__ bias, int K,
                                                      int bx, int by) {
  __shared__ bf16_t As[128][64];
  __shared__ bf16_t Bs[128][64];
  const int m0 = by * 128, n0 = bx * 128;
  const int t = threadIdx.x, w = t >> 6, lane = t & 63;
  const int wm = (w >> 1) * 64, wn = (w & 1) * 64;
  const int quad = lane >> 4, l16 = lane & 15;
  const int sra = lane >> 3;            // row 0..7 within an 8-row group
  const int sch = lane & 7;             // dest 16B chunk 0..7
  // source col chunk = sch ^ (row&7): LDS[row][q] = global[row][q^(row&7)]
  const bf16_t* Ag = A + (size_t)(m0 + w * 32 + sra) * lda + (sch ^ sra) * 8;
  const bf16_t* Bg = Bt + (size_t)(n0 + w * 32 + sra) * ldb + (sch ^ sra) * 8;
  bf16_t* la = &As[0][0] + w * 2048;    // wave-uniform; lane offset = lane*16B
  bf16_t* lb = &Bs[0][0] + w * 2048;

  f32x4 acc[4][4] = {};
  for (int k0 = 0; k0 < K; k0 += 64) {
    __syncthreads();
#pragma unroll
    for (int c = 0; c < 4; ++c)
      async_cp16(Ag + k0 + (size_t)(c * 8) * lda, la + c * 512);
#pragma unroll
    for (int c = 0; c < 4; ++c)
      async_cp16(Bg + k0 + (size_t)(c * 8) * ldb, lb + c * 512);
    __syncthreads();
#pragma unroll
    for (int ks = 0; ks < 2; ++ks) {
      bf16x8 af[4], bfr[4];
#pragma unroll
      for (int i = 0; i < 4; ++i)
        af[i] = *(const bf16x8*)&As[wm + i * 16 + l16][((ks * 4 + quad) ^ (l16 & 7)) * 8];
#pragma unroll
      for (int j = 0; j < 4; ++j)
        bfr[j] = *(const bf16x8*)&Bs[wn + j * 16 + l16][((ks * 4 + quad) ^ (l16 & 7)) * 8];
#pragma unroll
      for (int i = 0; i < 4; ++i)
#pragma unroll
        for (int j = 0; j < 4; ++j)
          acc[i][j] = __builtin_amdgcn_mfma_f32_16x16x32_bf16(af[i], bfr[j], acc[i][j], 0, 0, 0);
    }
  }
#pragma unroll
  for (int i = 0; i < 4; ++i) {
    int row = m0 + wm + i * 16 + quad * 4;
#pragma unroll
    for (int j = 0; j < 4; ++j) {
      int col = n0 + wn + j * 16 + l16;
      float bv = bias ? bias[col] : 0.f;
#pragma unroll
      for (int r = 0; r < 4; ++r)
        st_out(&C[(size_t)(row + r) * ldc + col], acc[i][j][r] + bv);
    }
  }
}

// 64x128 BK=32 variant (kept for gemm_wta's shape)
template <typename OutT>
static __device__ __forceinline__ void gemm_core_async64(const bf16_t* __restrict__ A, int lda,
                                                         const bf16_t* __restrict__ Bt, int ldb,
                                                         OutT* __restrict__ C, int ldc,
                                                         const float* __restrict__ bias, int K,
                                                         int bx, int by) {
  __shared__ bf16_t As[64][32];
  __shared__ bf16_t Bs[128][32];
  const int m0 = by * 64, n0 = bx * 128;
  const int t = threadIdx.x, w = t >> 6, lane = t & 63;
  const int wm = (w >> 1) * 32, wn = (w & 1) * 64;
  const int quad = lane >> 4, l16 = lane & 15;
  const int sra = lane >> 2, sca = (lane & 3) * 8;
  const bf16_t* Ag0 = A + (size_t)(m0 + w * 16 + sra) * lda + sca;
  const bf16_t* Bg0 = Bt + (size_t)(n0 + w * 16 + sra) * ldb + sca;
  const bf16_t* Bg1 = Bt + (size_t)(n0 + 64 + w * 16 + sra) * ldb + sca;
  bf16_t* la0 = &As[0][0] + w * 512;
  bf16_t* lb0 = &Bs[0][0] + w * 512;
  bf16_t* lb1 = &Bs[0][0] + 2048 + w * 512;

  f32x4 acc[2][4] = {};
  for (int k0 = 0; k0 < K; k0 += 32) {
    __syncthreads();
    async_cp16(Ag0 + k0, la0);
    async_cp16(Bg0 + k0, lb0);
    async_cp16(Bg1 + k0, lb1);
    __syncthreads();
    bf16x8 af[2], bfr[4];
#pragma unroll
    for (int i = 0; i < 2; ++i)
      af[i] = *(const bf16x8*)&As[wm + i * 16 + l16][quad * 8];
#pragma unroll
    for (int j = 0; j < 4; ++j)
      bfr[j] = *(const bf16x8*)&Bs[wn + j * 16 + l16][quad * 8];
#pragma unroll
    for (int i = 0; i < 2; ++i)
#pragma unroll
      for (int j = 0; j < 4; ++j)
        acc[i][j] = __builtin_amdgcn_mfma_f32_16x16x32_bf16(af[i], bfr[j], acc[i][j], 0, 0, 0);
  }
#pragma unroll
  for (int i = 0; i < 2; ++i) {
    int row = m0 + wm + i * 16 + quad * 4;
#pragma unroll
    for (int j = 0; j < 4; ++j) {
      int col = n0 + wn + j * 16 + l16;
      float bv = bias ? bias[col] : 0.f;
#pragma unroll
      for (int r = 0; r < 4; ++r)
        st_out(&C[(size_t)(row + r) * ldc + col], acc[i][j][r] + bv);
    }
  }
}

// XCD-aware swizzle (T1): dispatch id d runs on XCD d%8; remap so each
// XCD owns a contiguous tile range. Requires nwg % 8 == 0 (bijective).
__global__ __launch_bounds__(256) void gemm_qkv(const bf16_t* __restrict__ A,
                                                const bf16_t* __restrict__ Bt,
                                                bf16_t* __restrict__ C,
                                                const float* __restrict__ biasN) {
  int id = blockIdx.y * 26 + blockIdx.x;          // 832 = 8 * 104
  int nid = (id & 7) * 104 + (id >> 3);
  gemm_core_bk64<bf16_t>(A, 1024, Bt, 1024, C, 3328, biasN, 1024, nid % 26, nid / 26);
}

__global__ __launch_bounds__(256) void gemm_out(const bf16_t* __restrict__ A,
                                                const bf16_t* __restrict__ Bt,
                                                float* __restrict__ C,
                                                const float* __restrict__ bo) {
  int id = blockIdx.y * 8 + blockIdx.x;           // 256 = 8 * 32
  int nid = (id & 7) * 32 + (id >> 3);
  gemm_core_bk64<float>(A, 1024, Bt, 1024, C, 1024, bo, 1024, nid & 7, nid >> 3);
}

__global__ __launch_bounds__(256) void gemm_wta(const bf16_t* __restrict__ qtaT,
                                                const bf16_t* __restrict__ ktaT,
                                                const bf16_t* __restrict__ Wqb,
                                                const bf16_t* __restrict__ Wkb,
                                                bf16_t* __restrict__ BtExt) {
  int z = blockIdx.z;
  gemm_core_async64<bf16_t>(z ? ktaT : qtaT, 1024, z ? Wkb : Wqb, 1024,
                            BtExt + (size_t)(3072 + z * 128) * 1024, 1024,
                            nullptr, 1024, blockIdx.x, blockIdx.y);
}

// =====================================================================
// fused torsion + q pre-scale by log2(e)/8
// =====================================================================
__global__ __launch_bounds__(256) void lin_torsion_fused(const bf16_t* __restrict__ qtbT,
                                                         const bf16_t* __restrict__ ktbT,
                                                         bf16_t* __restrict__ qkv,
                                                         const float* __restrict__ coupling) {
  __shared__ bf16_t As[128][136];
  __shared__ bf16_t Bs0[128][72];
  __shared__ bf16_t Bs1[128][72];
  const int z = blockIdx.z;
  const bf16_t* Low = qkv + 3072 + z * 128;
  const bf16_t* Tb = z ? ktbT : qtbT;
  bf16_t* X = qkv + z * 1024;

  const int m0 = blockIdx.y * 128, n0 = blockIdx.x * 128;
  const int t = threadIdx.x, w = t >> 6, lane = t & 63;
  const int wm = (w >> 1) * 64, wn = (w & 1) * 64;
  const int quad = lane >> 4, l16 = lane & 15;

  {
    const int sr = t >> 1, sc = (t & 1) * 64;
    const bf16_t* Ag = Low + (size_t)(m0 + sr) * 3328 + sc;
#pragma unroll
    for (int i = 0; i < 8; ++i)
      *(float4*)&As[sr][sc + 8 * i] = *(const float4*)(Ag + 8 * i);
    const int br = t >> 1, bc = (t & 1) * 32;
    const bf16_t* Bg0 = Tb + (size_t)(n0 + br) * 64 + bc;
    const bf16_t* Bg1 = Bg0 + 65536;
#pragma unroll
    for (int i = 0; i < 4; ++i) {
      *(float4*)&Bs0[br][bc + 8 * i] = *(const float4*)(Bg0 + 8 * i);
      *(float4*)&Bs1[br][bc + 8 * i] = *(const float4*)(Bg1 + 8 * i);
    }
  }
  __syncthreads();

  f32x4 acc0[4][4] = {}, acc1[4][4] = {};
#pragma unroll
  for (int ks = 0; ks < 2; ++ks) {
    bf16x8 a0[4], a1[4];
#pragma unroll
    for (int i = 0; i < 4; ++i) {
      a0[i] = *(const bf16x8*)&As[wm + i * 16 + l16][ks * 32 + quad * 8];
      a1[i] = *(const bf16x8*)&As[wm + i * 16 + l16][64 + ks * 32 + quad * 8];
    }
#pragma unroll
    for (int j = 0; j < 4; ++j) {
      bf16x8 b0 = *(const bf16x8*)&Bs0[wn + j * 16 + l16][ks * 32 + quad * 8];
      bf16x8 b1 = *(const bf16x8*)&Bs1[wn + j * 16 + l16][ks * 32 + quad * 8];
#pragma unroll
      for (int i = 0; i < 4; ++i) {
        acc0[i][j] = __builtin_amdgcn_mfma_f32_16x16x32_bf16(a0[i], b0, acc0[i][j], 0, 0, 0);
        acc1[i][j] = __builtin_amdgcn_mfma_f32_16x16x32_bf16(a1[i], b1, acc1[i][j], 0, 0, 0);
      }
    }
  }

  const float PI2 = 6.283185307179586f;
  const float sig = 1.f / (1.f + __expf(-coupling[0]));
  const float scale = z ? 1.f : 0.1803368801111204f;
#pragma unroll
  for (int i = 0; i < 4; ++i) {
#pragma unroll
    for (int j = 0; j < 4; ++j) {
#pragma unroll
      for (int r = 0; r < 4; ++r) {
        int row = m0 + wm + i * 16 + quad * 4 + r;
        int col = n0 + wn + j * 16 + l16;
        size_t idx = (size_t)row * 3328 + col;
        float l1 = acc0[i][j][r], l2 = acc1[i][j][r];
        float corr = __sinf(PI2 * l1) * l1 + __sinf(2.f * PI2 * l2) * l2 * 0.5f;
        X[idx] = (bf16_t)(((float)X[idx] + sig * corr) * scale);
      }
    }
  }
}

// =====================================================================
// Flash attention v15 = v14 (KV-aware XCD remap: FETCH 69.7->20.7 MB,
// verified) + epilogue fix. v14's regression was NOT the remap's loop
// behavior (MfmaUtil/VALUBusy scaled exactly with dur => loop speed
// unchanged) but an epilogue RMW storm: each 128B aout line was written
// in 4x32B chunks across jd phases; with L2 now full of hot K/V, the
// partial lines evicted between phases -> WRITE_SIZE 8.2->38.7 MB.
// Fix: buffer the 4 packed uint4 per thread, store all 4 back-to-back
// after the LDS phases -> each line written once, in one burst.
// =====================================================================
__global__ __launch_bounds__(256, 2) void flash_attn(const bf16_t* __restrict__ qkv,
                                                     bf16_t* __restrict__ aout) {
  constexpr int LD = 3328, SEQ = 2048;
  const int id = blockIdx.x + (blockIdx.y << 4);   // 0..511, x fastest
  const int qb = id >> 5;                          // 0..15
  const int bh = (id & 7) * 4 + ((id >> 3) & 3);   // XCD-major bh grouping
  const int b = bh >> 4, h = bh & 15;
  const size_t base = (size_t)b * SEQ * LD + h * 64;
  const bf16_t* Qg = qkv + base;
  const bf16_t* Kg = qkv + base + 1024;
  const bf16_t* Vg = qkv + base + 2048;

  __shared__ __align__(16) unsigned char smem[67584];
  bf16_t(*VT0)[136] = (bf16_t(*)[136])smem;            // V slot 0 (even tiles)
  bf16_t(*VT1)[136] = (bf16_t(*)[136])(smem + 17408);  // V slot 1 (odd tiles)
  bf16_t* Kl0 = (bf16_t*)(smem + 34816);               // K slot 0 [128][64] swz
  bf16_t* Kl1 = (bf16_t*)(smem + 51200);               // K slot 1
  float* LDSo = (float*)smem;                // [256][24] f32, epilogue
  float* Lred = (float*)(smem + 24576);      // [1024] f32, epilogue
  float* invL = (float*)(smem + 28672);      // [128] f32, epilogue

  const int t = threadIdx.x, w = t >> 6, lane = t & 63;
  const int kw = w >> 1, qw = w & 1;
  const int quad = lane >> 4, l16 = lane & 15;
  const int q0 = qb * 128;

  // ---- Q fragments direct from global ----
  bf16x8 qf[4][2];
  {
    const bf16_t* Qrow = Qg + (size_t)(q0 + qw * 64 + l16) * LD + quad * 8;
#pragma unroll
    for (int nf = 0; nf < 4; ++nf)
#pragma unroll
      for (int ks = 0; ks < 2; ++ks)
        qf[nf][ks] = *(const bf16x8*)(Qrow + (size_t)(nf * 16) * LD + ks * 32);
  }

  f32x4 o[4][4] = {};
  float l_part[4] = {0.f, 0.f, 0.f, 0.f};

  const int vg = t >> 3, vcb = (t & 7) * 8;
  // key-slot permutation (PV B-fragment order) ^ 3-bit row-XOR bank swizzle
  const int colb = (((vg >> 3) << 5) | ((vg & 3) << 3) | (((vg >> 2) & 1) << 2)) ^ ((t & 7) << 3);
  const bf16_t* Vbase = Vg + (size_t)(vg * 4) * LD + vcb;

  // K staging geometry: LDS byte o = c*4096 + w*1024 + lane*16 decodes to
  // row = c*32 + w*8 + (lane>>3), stored 16B-chunk = lane&7. Source chunk
  // for that slot = (lane&7) ^ (row&7) = (lane&7) ^ (lane>>3).
  const bf16_t* Kstg = Kg + (size_t)(w * 8 + (lane >> 3)) * LD + ((lane & 7) ^ (lane >> 3)) * 8;

  float4 vr[4];  // V stage regs, one tile in flight (only loop-carried VMEM regs)

  // ---- prologue: DMA K tile 0 into Kl0; stage V tile 0 into VT0;
  //      issue vr loads for tile 1 ----
  {
    bf16_t* dst = Kl0 + w * 512;
#pragma unroll
    for (int c = 0; c < 4; ++c)
      async_cp16(Kstg + (size_t)(c * 32) * LD, dst + c * 2048);
  }
#pragma unroll
  for (int kk = 0; kk < 4; ++kk)
    vr[kk] = *(const float4*)(Vbase + (size_t)kk * LD);
#pragma unroll
  for (int cc = 0; cc < 8; ++cc) {
    union { bf16_t h[4]; uint2 u; } pk;
#pragma unroll
    for (int kk = 0; kk < 4; ++kk) pk.h[kk] = ((const bf16_t*)&vr[kk])[cc];
    *(uint2*)&VT0[vcb + cc][colb] = pk.u;
  }
#pragma unroll
  for (int kk = 0; kk < 4; ++kk)
    vr[kk] = *(const float4*)(Vbase + (size_t)(128 + kk) * LD);
  __syncthreads();  // VT0 + Kl0 ready (vmcnt drained); vr loads in flight

  for (int k0 = 0; k0 < SEQ; k0 += 128) {
    const int cur = (k0 >> 7) & 1;
    bf16_t(*VTc)[136] = cur ? VT1 : VT0;
    bf16_t(*VTn)[136] = cur ? VT0 : VT1;
    const bf16_t* Kc = cur ? Kl1 : Kl0;

    // ---- DMA next K tile into the other slot (completes by next barrier) ----
    if (k0 + 128 < SEQ) {
      bf16_t* dst = (cur ? Kl0 : Kl1) + w * 512;
#pragma unroll
      for (int c = 0; c < 4; ++c)
        async_cp16(Kstg + (size_t)(k0 + 128 + c * 32) * LD, dst + c * 2048);
    }

    // ---- K fragments from LDS (swizzled read; conflict-free) ----
    bf16x8 kf[4][2];
#pragma unroll
    for (int jk = 0; jk < 4; ++jk) {
      int row = kw * 64 + jk * 16 + l16;
#pragma unroll
      for (int ks = 0; ks < 2; ++ks) {
        int ch = (ks * 4 + quad) ^ (l16 & 7);
        kf[jk][ks] = *(const bf16x8*)&Kc[row * 64 + ch * 8];
      }
    }

    // ---- QK^T ----
    f32x4 st[4][4] = {};
    __builtin_amdgcn_s_setprio(1);
#pragma unroll
    for (int ks = 0; ks < 2; ++ks)
#pragma unroll
      for (int jk = 0; jk < 4; ++jk)
#pragma unroll
        for (int nf = 0; nf < 4; ++nf)
          st[jk][nf] = __builtin_amdgcn_mfma_f32_16x16x32_bf16(kf[jk][ks], qf[nf][ks], st[jk][nf], 0, 0, 0);
    __builtin_amdgcn_s_setprio(0);

    // ---- softmax + pack to bf16 (B-fragment key order) ----
    bf16x8 Pp[2][4];
#pragma unroll
    for (int g = 0; g < 2; ++g)
#pragma unroll
      for (int nf = 0; nf < 4; ++nf) {
        union { bf16_t hh[8]; bf16x8 v; } ph;
#pragma unroll
        for (int b2 = 0; b2 < 2; ++b2)
#pragma unroll
          for (int r = 0; r < 4; ++r) {
            float p = exp2f(st[g * 2 + b2][nf][r]);
            l_part[nf] += p;
            ph.hh[b2 * 4 + r] = (bf16_t)p;
          }
        Pp[g][nf] = ph.v;
      }

    // ---- stage: repack vr (tile k0+128) -> VTn, issue V loads k0+256.
    //      ds_writes overlap the PV MFMAs below. ----
    if (k0 + 128 < SEQ) {
#pragma unroll
      for (int cc = 0; cc < 8; ++cc) {
        union { bf16_t h[4]; uint2 u; } pk;
#pragma unroll
        for (int kk = 0; kk < 4; ++kk) pk.h[kk] = ((const bf16_t*)&vr[kk])[cc];
        *(uint2*)&VTn[vcb + cc][colb] = pk.u;
      }
      if (k0 + 256 < SEQ) {
#pragma unroll
        for (int kk = 0; kk < 4; ++kk)
          vr[kk] = *(const float4*)(Vbase + (size_t)(k0 + 256 + kk) * LD);
      }
    }

    // ---- PV from VTc (written last iter; ready since barrier) ----
#pragma unroll
    for (int g = 0; g < 2; ++g) {
      bf16x8 vf[4];
#pragma unroll
      for (int jd = 0; jd < 4; ++jd) {
        int row = jd * 16 + l16;
        int col = (kw * 64 + g * 32 + quad * 8) ^ ((((row >> 3) & 7)) << 3);
        vf[jd] = *(const bf16x8*)&VTc[row][col];
      }
      __builtin_amdgcn_s_setprio(1);
#pragma unroll
      for (int jd = 0; jd < 4; ++jd)
#pragma unroll
        for (int nf = 0; nf < 4; ++nf)
          o[jd][nf] = __builtin_amdgcn_mfma_f32_16x16x32_bf16(vf[jd], Pp[g][nf], o[jd][nf], 0, 0, 0);
      __builtin_amdgcn_s_setprio(0);
    }

    // ---- counted-vmcnt barrier (T4): drain K-DMA (+ repack ds_writes
    // via lgkmcnt) but let the 4 vr loads stay in flight. vr are the 4
    // NEWEST vmem ops this iter (issued after the K-DMA), so vmcnt(4)
    // waits exactly for everything older. Tail iters without vr loads
    // fall back to a full drain so the last K-DMA is covered.
    __builtin_amdgcn_sched_barrier(0);
    if (k0 + 256 < SEQ)
      asm volatile("s_waitcnt vmcnt(4) lgkmcnt(0)" ::: "memory");
    else
      asm volatile("s_waitcnt vmcnt(0) lgkmcnt(0)" ::: "memory");
    __builtin_amdgcn_s_barrier();
    __builtin_amdgcn_sched_barrier(0);
  }

  // ---- epilogue: reduce l and O across kw/quad, divide; BUFFER the 4
  // packed stores and issue them back-to-back so each 128B aout line is
  // written in one burst (no partial-line eviction/RMW). ----
#pragma unroll
  for (int nf = 0; nf < 4; ++nf)
    Lred[((kw * 2 + qw) * 4 + quad) * 64 + nf * 16 + l16] = l_part[nf];
  __syncthreads();
  if (t < 128) {
    int qw2 = t >> 6, ql = t & 63;
    float s = 0.f;
#pragma unroll
    for (int kw2 = 0; kw2 < 2; ++kw2)
#pragma unroll
      for (int qd = 0; qd < 4; ++qd)
        s += Lred[((kw2 * 2 + qw2) * 4 + qd) * 64 + ql];
    invL[t] = 1.f / s;
  }
  __syncthreads();

  const int rq = t >> 1, rc0 = (t & 1) * 8;
  uint4 obuf[4];
#pragma unroll
  for (int jd = 0; jd < 4; ++jd) {
#pragma unroll
    for (int nf = 0; nf < 4; ++nf)
      *(f32x4*)&LDSo[(size_t)(kw * 128 + qw * 64 + nf * 16 + l16) * 24 + quad * 4] = o[jd][nf];
    __syncthreads();
    f32x4 a0 = *(const f32x4*)&LDSo[(size_t)rq * 24 + rc0];
    f32x4 a1 = *(const f32x4*)&LDSo[(size_t)(128 + rq) * 24 + rc0];
    f32x4 b0 = *(const f32x4*)&LDSo[(size_t)rq * 24 + rc0 + 4];
    f32x4 b1 = *(const f32x4*)&LDSo[(size_t)(128 + rq) * 24 + rc0 + 4];
    float iv = invL[rq];
    union { bf16_t h[8]; uint4 u; } pk;
#pragma unroll
    for (int r = 0; r < 4; ++r) {
      pk.h[r] = (bf16_t)((a0[r] + a1[r]) * iv);
      pk.h[4 + r] = (bf16_t)((b0[r] + b1[r]) * iv);
    }
    obuf[jd] = pk.u;
    if (jd < 3) __syncthreads();
  }
  {
    bf16_t* orow = aout + (size_t)(b * SEQ + q0 + rq) * 1024 + h * 64 + rc0;
#pragma unroll
    for (int jd = 0; jd < 4; ++jd)
      *(uint4*)(orow + jd * 16) = obuf[jd];
  }
}

// =====================================================================
// host launch
// =====================================================================
extern "C" void kernel_launch(void* const* d_in, const int* in_sizes, int n_in,
                              void* d_out, int out_size, void* d_ws, size_t ws_size,
                              hipStream_t stream) {
  const float* hs   = (const float*)d_in[0];
  const float* Wq   = (const float*)d_in[1];
  const float* bq   = (const float*)d_in[2];
  const float* Wk   = (const float*)d_in[3];
  const float* bk   = (const float*)d_in[4];
  const float* Wv   = (const float*)d_in[5];
  const float* bv   = (const float*)d_in[6];
  const float* Wo   = (const float*)d_in[7];
  const float* bo   = (const float*)d_in[8];
  const float* qta  = (const float*)d_in[9];
  const float* qtb  = (const float*)d_in[10];
  const float* kta  = (const float*)d_in[11];
  const float* ktb  = (const float*)d_in[12];
  const float* coup = (const float*)d_in[13];
  float* out = (float*)d_out;

  uint8_t* ws = (uint8_t*)d_ws;
  bf16_t* hsb   = (bf16_t*)(ws);              // dead after gemm_qkv -> aout
  bf16_t* aout  = (bf16_t*)(ws);              // flash output overlays hsb
  bf16_t* BtExt = (bf16_t*)(ws + 8388608);    // [3328][1024]
  bf16_t* WoT   = (bf16_t*)(ws + 16777216);   // 2 MB
  float*  biasN = (float*)(ws + 18874368);    // 16 KB
  bf16_t* qkv   = (bf16_t*)(ws + 18890752);   // [4096][3328] 27.3 MB
  bf16_t* Wqb   = (bf16_t*)(ws + 46153728);   // prep scratch
  bf16_t* Wkb   = (bf16_t*)(ws + 48250880);
  bf16_t* qtaT  = (bf16_t*)(ws + 50348032);
  bf16_t* ktaT  = (bf16_t*)(ws + 50610176);
  bf16_t* qtbT  = (bf16_t*)(ws + 50872320);
  bf16_t* ktbT  = (bf16_t*)(ws + 51134464);

  dim3 b256(256);

  prep<<<6684, b256, 0, stream>>>(hs, hsb, Wq, Wk, Wv, Wo, BtExt, WoT, Wqb, Wkb,
                                  qta, kta, qtaT, ktaT, qtb, ktb, qtbT, ktbT,
                                  bq, bk, bv, biasN);
  gemm_wta<<<dim3(8, 2, 2), b256, 0, stream>>>(qtaT, ktaT, Wqb, Wkb, BtExt);
  gemm_qkv<<<dim3(26, 32), b256, 0, stream>>>(hsb, BtExt, qkv, biasN);
  lin_torsion_fused<<<dim3(8, 32, 2), b256, 0, stream>>>(qtbT, ktbT, qkv, coup);
  flash_attn<<<dim3(16, 32), b256, 0, stream>>>(qkv, aout);
  gemm_out<<<dim3(8, 32), b256, 0, stream>>>(aout, WoT, out, bo);
}

// Round 10
// 261.805 us; speedup vs baseline: 1.1469x; 1.1469x over previous
//
#include <hip/hip_runtime.h>
#include <hip/hip_bf16.h>
#include <cstdint>
#include <cstddef>

typedef __bf16 bf16_t;
typedef __bf16 bf16x8 __attribute__((ext_vector_type(8)));
typedef float f32x4 __attribute__((ext_vector_type(4)));

static __device__ __forceinline__ void st_out(float* p, float v) { *p = v; }
static __device__ __forceinline__ void st_out(bf16_t* p, float v) { *p = (bf16_t)v; }

static __device__ __forceinline__ void async_cp16(const bf16_t* g, bf16_t* l) {
  __builtin_amdgcn_global_load_lds(
      (const __attribute__((address_space(1))) void*)g,
      (__attribute__((address_space(3))) void*)l, 16, 0, 0);
}

// =====================================================================
// prep: all setup work in ONE launch. 1D grid, block ranges:
// [0,2048) cvt hs | [2048,6144) W transposes | [6144,6400) ta^T
// [6400,6656) tb^T | [6656,6668) bias concat | [6668,6684) low bias
// =====================================================================
__global__ __launch_bounds__(256) void prep(const float* __restrict__ hs, bf16_t* __restrict__ hsb,
                                            const float* __restrict__ Wq, const float* __restrict__ Wk,
                                            const float* __restrict__ Wv, const float* __restrict__ Wo,
                                            bf16_t* __restrict__ BtExt, bf16_t* __restrict__ WoT,
                                            bf16_t* __restrict__ Wqb, bf16_t* __restrict__ Wkb,
                                            const float* __restrict__ qta, const float* __restrict__ kta,
                                            bf16_t* __restrict__ qtaT, bf16_t* __restrict__ ktaT,
                                            const float* __restrict__ qtb, const float* __restrict__ ktb,
                                            bf16_t* __restrict__ qtbT, bf16_t* __restrict__ ktbT,
                                            const float* __restrict__ bq, const float* __restrict__ bk,
                                            const float* __restrict__ bv, float* __restrict__ biasN) {
  __shared__ float tile[32][33];
  const int bid = blockIdx.x, t = threadIdx.x;
  const int tx = t & 31, ty = t >> 5;

  if (bid < 2048) {  // ---- cvt ----
    int i = (bid * 256 + t) * 8;
    float4 a = *(const float4*)(hs + i);
    float4 b = *(const float4*)(hs + i + 4);
    union { bf16_t h[8]; uint4 u; } p;
    p.h[0] = (bf16_t)a.x; p.h[1] = (bf16_t)a.y; p.h[2] = (bf16_t)a.z; p.h[3] = (bf16_t)a.w;
    p.h[4] = (bf16_t)b.x; p.h[5] = (bf16_t)b.y; p.h[6] = (bf16_t)b.z; p.h[7] = (bf16_t)b.w;
    *(uint4*)(hsb + i) = p.u;
  } else if (bid < 6144) {  // ---- weight transposes ----
    int r = bid - 2048, z = r >> 10, r10 = r & 1023;
    int bx = (r10 & 31) * 32, by = (r10 >> 5) * 32;
    const float* src = z == 0 ? Wq : z == 1 ? Wk : z == 2 ? Wv : Wo;
    bf16_t* dst = z == 3 ? WoT : BtExt + (size_t)z * 1048576;
    bf16_t* sd = z == 0 ? Wqb : z == 1 ? Wkb : nullptr;
#pragma unroll
    for (int i = 0; i < 4; ++i) {
      float v = src[(size_t)(by + ty + i * 8) * 1024 + bx + tx];
      tile[ty + i * 8][tx] = v;
      if (sd) sd[(size_t)(by + ty + i * 8) * 1024 + bx + tx] = (bf16_t)v;
    }
    __syncthreads();
#pragma unroll
    for (int i = 0; i < 4; ++i)
      dst[(size_t)(bx + ty + i * 8) * 1024 + by + tx] = (bf16_t)tile[tx][ty + i * 8];
  } else if (bid < 6400) {  // ---- ta: [1024][64] -> [64][1024] ----
    int r = bid - 6144, z = r >> 6, r6 = r & 63;
    int bx = (r6 & 1) * 32, by = (r6 >> 1) * 32;
    const float* src = ((z >> 1) ? kta : qta) + (size_t)(z & 1) * 65536;
    bf16_t* dst = ((z >> 1) ? ktaT : qtaT) + (size_t)(z & 1) * 65536;
#pragma unroll
    for (int i = 0; i < 4; ++i)
      tile[ty + i * 8][tx] = src[(size_t)(by + ty + i * 8) * 64 + bx + tx];
    __syncthreads();
#pragma unroll
    for (int i = 0; i < 4; ++i)
      dst[(size_t)(bx + ty + i * 8) * 1024 + by + tx] = (bf16_t)tile[tx][ty + i * 8];
  } else if (bid < 6656) {  // ---- tb: [64][1024] -> [1024][64] ----
    int r = bid - 6400, z = r >> 6, r6 = r & 63;
    int bx = (r6 & 31) * 32, by = (r6 >> 5) * 32;
    const float* src = ((z >> 1) ? ktb : qtb) + (size_t)(z & 1) * 65536;
    bf16_t* dst = ((z >> 1) ? ktbT : qtbT) + (size_t)(z & 1) * 65536;
#pragma unroll
    for (int i = 0; i < 4; ++i)
      tile[ty + i * 8][tx] = src[(size_t)(by + ty + i * 8) * 1024 + bx + tx];
    __syncthreads();
#pragma unroll
    for (int i = 0; i < 4; ++i)
      dst[(size_t)(bx + ty + i * 8) * 64 + by + tx] = (bf16_t)tile[tx][ty + i * 8];
  } else if (bid < 6668) {  // ---- bias concat ----
    int i = (bid - 6656) * 256 + t;
    biasN[i] = (i < 1024) ? bq[i] : (i < 2048 ? bk[i - 1024] : bv[i - 2048]);
  } else {  // ---- low bias: 16 blocks x 16 j-outputs, 16 h-lanes each ----
    int B = bid - 6668;                 // 0..15
    int j = B * 16 + (t >> 4);          // output index 0..255
    int hoff = t & 15;
    const float* b = (j < 128) ? bq : bk;
    const float* ta = ((j < 128) ? qta : kta) + (size_t)((j >> 6) & 1) * 65536;
    int rr = j & 63;
    float s = 0.f;
#pragma unroll 4
    for (int i = 0; i < 64; ++i) {
      int h = hoff + i * 16;
      s += b[h] * ta[(size_t)h * 64 + rr];
    }
    // reduce across the 16 h-lanes (xor widths 1,2,4,8 stay in-wave)
#pragma unroll
    for (int m = 8; m >= 1; m >>= 1) s += __shfl_xor(s, m, 64);
    if (hoff == 0) biasN[3072 + j] = s;
  }
}

// =====================================================================
// 128x128 BK=64 async GEMM core: m97 fragment layout, 64-wide K-steps
// (half the barrier pairs). Bank swizzle via pre-swizzled global SOURCE
// + swizzled read (rule #21), chunk ^= row&7; DMA dest stays linear.
// =====================================================================
template <typename OutT>
static __device__ __forceinline__ void gemm_core_bk64(const bf16_t* __restrict__ A, int lda,
                                                      const bf16_t* __restrict__ Bt, int ldb,
                                                      OutT* __restrict__ C, int ldc,
                                                      const float* __restrict__ bias, int K,
                                                      int bx, int by) {
  __shared__ bf16_t As[128][64];
  __shared__ bf16_t Bs[128][64];
  const int m0 = by * 128, n0 = bx * 128;
  const int t = threadIdx.x, w = t >> 6, lane = t & 63;
  const int wm = (w >> 1) * 64, wn = (w & 1) * 64;
  const int quad = lane >> 4, l16 = lane & 15;
  const int sra = lane >> 3;            // row 0..7 within an 8-row group
  const int sch = lane & 7;             // dest 16B chunk 0..7
  // source col chunk = sch ^ (row&7): LDS[row][q] = global[row][q^(row&7)]
  const bf16_t* Ag = A + (size_t)(m0 + w * 32 + sra) * lda + (sch ^ sra) * 8;
  const bf16_t* Bg = Bt + (size_t)(n0 + w * 32 + sra) * ldb + (sch ^ sra) * 8;
  bf16_t* la = &As[0][0] + w * 2048;    // wave-uniform; lane offset = lane*16B
  bf16_t* lb = &Bs[0][0] + w * 2048;

  f32x4 acc[4][4] = {};
  for (int k0 = 0; k0 < K; k0 += 64) {
    __syncthreads();
#pragma unroll
    for (int c = 0; c < 4; ++c)
      async_cp16(Ag + k0 + (size_t)(c * 8) * lda, la + c * 512);
#pragma unroll
    for (int c = 0; c < 4; ++c)
      async_cp16(Bg + k0 + (size_t)(c * 8) * ldb, lb + c * 512);
    __syncthreads();
#pragma unroll
    for (int ks = 0; ks < 2; ++ks) {
      bf16x8 af[4], bfr[4];
#pragma unroll
      for (int i = 0; i < 4; ++i)
        af[i] = *(const bf16x8*)&As[wm + i * 16 + l16][((ks * 4 + quad) ^ (l16 & 7)) * 8];
#pragma unroll
      for (int j = 0; j < 4; ++j)
        bfr[j] = *(const bf16x8*)&Bs[wn + j * 16 + l16][((ks * 4 + quad) ^ (l16 & 7)) * 8];
#pragma unroll
      for (int i = 0; i < 4; ++i)
#pragma unroll
        for (int j = 0; j < 4; ++j)
          acc[i][j] = __builtin_amdgcn_mfma_f32_16x16x32_bf16(af[i], bfr[j], acc[i][j], 0, 0, 0);
    }
  }
#pragma unroll
  for (int i = 0; i < 4; ++i) {
    int row = m0 + wm + i * 16 + quad * 4;
#pragma unroll
    for (int j = 0; j < 4; ++j) {
      int col = n0 + wn + j * 16 + l16;
      float bv = bias ? bias[col] : 0.f;
#pragma unroll
      for (int r = 0; r < 4; ++r)
        st_out(&C[(size_t)(row + r) * ldc + col], acc[i][j][r] + bv);
    }
  }
}

// 64x128 BK=32 variant (kept for gemm_wta's shape)
template <typename OutT>
static __device__ __forceinline__ void gemm_core_async64(const bf16_t* __restrict__ A, int lda,
                                                         const bf16_t* __restrict__ Bt, int ldb,
                                                         OutT* __restrict__ C, int ldc,
                                                         const float* __restrict__ bias, int K,
                                                         int bx, int by) {
  __shared__ bf16_t As[64][32];
  __shared__ bf16_t Bs[128][32];
  const int m0 = by * 64, n0 = bx * 128;
  const int t = threadIdx.x, w = t >> 6, lane = t & 63;
  const int wm = (w >> 1) * 32, wn = (w & 1) * 64;
  const int quad = lane >> 4, l16 = lane & 15;
  const int sra = lane >> 2, sca = (lane & 3) * 8;
  const bf16_t* Ag0 = A + (size_t)(m0 + w * 16 + sra) * lda + sca;
  const bf16_t* Bg0 = Bt + (size_t)(n0 + w * 16 + sra) * ldb + sca;
  const bf16_t* Bg1 = Bt + (size_t)(n0 + 64 + w * 16 + sra) * ldb + sca;
  bf16_t* la0 = &As[0][0] + w * 512;
  bf16_t* lb0 = &Bs[0][0] + w * 512;
  bf16_t* lb1 = &Bs[0][0] + 2048 + w * 512;

  f32x4 acc[2][4] = {};
  for (int k0 = 0; k0 < K; k0 += 32) {
    __syncthreads();
    async_cp16(Ag0 + k0, la0);
    async_cp16(Bg0 + k0, lb0);
    async_cp16(Bg1 + k0, lb1);
    __syncthreads();
    bf16x8 af[2], bfr[4];
#pragma unroll
    for (int i = 0; i < 2; ++i)
      af[i] = *(const bf16x8*)&As[wm + i * 16 + l16][quad * 8];
#pragma unroll
    for (int j = 0; j < 4; ++j)
      bfr[j] = *(const bf16x8*)&Bs[wn + j * 16 + l16][quad * 8];
#pragma unroll
    for (int i = 0; i < 2; ++i)
#pragma unroll
      for (int j = 0; j < 4; ++j)
        acc[i][j] = __builtin_amdgcn_mfma_f32_16x16x32_bf16(af[i], bfr[j], acc[i][j], 0, 0, 0);
  }
#pragma unroll
  for (int i = 0; i < 2; ++i) {
    int row = m0 + wm + i * 16 + quad * 4;
#pragma unroll
    for (int j = 0; j < 4; ++j) {
      int col = n0 + wn + j * 16 + l16;
      float bv = bias ? bias[col] : 0.f;
#pragma unroll
      for (int r = 0; r < 4; ++r)
        st_out(&C[(size_t)(row + r) * ldc + col], acc[i][j][r] + bv);
    }
  }
}

// XCD-aware swizzle (T1): dispatch id d runs on XCD d%8; remap so each
// XCD owns a contiguous tile range. Requires nwg % 8 == 0 (bijective).
__global__ __launch_bounds__(256) void gemm_qkv(const bf16_t* __restrict__ A,
                                                const bf16_t* __restrict__ Bt,
                                                bf16_t* __restrict__ C,
                                                const float* __restrict__ biasN) {
  int id = blockIdx.y * 26 + blockIdx.x;          // 832 = 8 * 104
  int nid = (id & 7) * 104 + (id >> 3);
  gemm_core_bk64<bf16_t>(A, 1024, Bt, 1024, C, 3328, biasN, 1024, nid % 26, nid / 26);
}

__global__ __launch_bounds__(256) void gemm_out(const bf16_t* __restrict__ A,
                                                const bf16_t* __restrict__ Bt,
                                                float* __restrict__ C,
                                                const float* __restrict__ bo) {
  int id = blockIdx.y * 8 + blockIdx.x;           // 256 = 8 * 32
  int nid = (id & 7) * 32 + (id >> 3);
  gemm_core_bk64<float>(A, 1024, Bt, 1024, C, 1024, bo, 1024, nid & 7, nid >> 3);
}

__global__ __launch_bounds__(256) void gemm_wta(const bf16_t* __restrict__ qtaT,
                                                const bf16_t* __restrict__ ktaT,
                                                const bf16_t* __restrict__ Wqb,
                                                const bf16_t* __restrict__ Wkb,
                                                bf16_t* __restrict__ BtExt) {
  int z = blockIdx.z;
  gemm_core_async64<bf16_t>(z ? ktaT : qtaT, 1024, z ? Wkb : Wqb, 1024,
                            BtExt + (size_t)(3072 + z * 128) * 1024, 1024,
                            nullptr, 1024, blockIdx.x, blockIdx.y);
}

// =====================================================================
// fused torsion + q pre-scale by log2(e)/8
// =====================================================================
__global__ __launch_bounds__(256) void lin_torsion_fused(const bf16_t* __restrict__ qtbT,
                                                         const bf16_t* __restrict__ ktbT,
                                                         bf16_t* __restrict__ qkv,
                                                         const float* __restrict__ coupling) {
  __shared__ bf16_t As[128][136];
  __shared__ bf16_t Bs0[128][72];
  __shared__ bf16_t Bs1[128][72];
  const int z = blockIdx.z;
  const bf16_t* Low = qkv + 3072 + z * 128;
  const bf16_t* Tb = z ? ktbT : qtbT;
  bf16_t* X = qkv + z * 1024;

  const int m0 = blockIdx.y * 128, n0 = blockIdx.x * 128;
  const int t = threadIdx.x, w = t >> 6, lane = t & 63;
  const int wm = (w >> 1) * 64, wn = (w & 1) * 64;
  const int quad = lane >> 4, l16 = lane & 15;

  {
    const int sr = t >> 1, sc = (t & 1) * 64;
    const bf16_t* Ag = Low + (size_t)(m0 + sr) * 3328 + sc;
#pragma unroll
    for (int i = 0; i < 8; ++i)
      *(float4*)&As[sr][sc + 8 * i] = *(const float4*)(Ag + 8 * i);
    const int br = t >> 1, bc = (t & 1) * 32;
    const bf16_t* Bg0 = Tb + (size_t)(n0 + br) * 64 + bc;
    const bf16_t* Bg1 = Bg0 + 65536;
#pragma unroll
    for (int i = 0; i < 4; ++i) {
      *(float4*)&Bs0[br][bc + 8 * i] = *(const float4*)(Bg0 + 8 * i);
      *(float4*)&Bs1[br][bc + 8 * i] = *(const float4*)(Bg1 + 8 * i);
    }
  }
  __syncthreads();

  f32x4 acc0[4][4] = {}, acc1[4][4] = {};
#pragma unroll
  for (int ks = 0; ks < 2; ++ks) {
    bf16x8 a0[4], a1[4];
#pragma unroll
    for (int i = 0; i < 4; ++i) {
      a0[i] = *(const bf16x8*)&As[wm + i * 16 + l16][ks * 32 + quad * 8];
      a1[i] = *(const bf16x8*)&As[wm + i * 16 + l16][64 + ks * 32 + quad * 8];
    }
#pragma unroll
    for (int j = 0; j < 4; ++j) {
      bf16x8 b0 = *(const bf16x8*)&Bs0[wn + j * 16 + l16][ks * 32 + quad * 8];
      bf16x8 b1 = *(const bf16x8*)&Bs1[wn + j * 16 + l16][ks * 32 + quad * 8];
#pragma unroll
      for (int i = 0; i < 4; ++i) {
        acc0[i][j] = __builtin_amdgcn_mfma_f32_16x16x32_bf16(a0[i], b0, acc0[i][j], 0, 0, 0);
        acc1[i][j] = __builtin_amdgcn_mfma_f32_16x16x32_bf16(a1[i], b1, acc1[i][j], 0, 0, 0);
      }
    }
  }

  const float PI2 = 6.283185307179586f;
  const float sig = 1.f / (1.f + __expf(-coupling[0]));
  const float scale = z ? 1.f : 0.1803368801111204f;
#pragma unroll
  for (int i = 0; i < 4; ++i) {
#pragma unroll
    for (int j = 0; j < 4; ++j) {
#pragma unroll
      for (int r = 0; r < 4; ++r) {
        int row = m0 + wm + i * 16 + quad * 4 + r;
        int col = n0 + wn + j * 16 + l16;
        size_t idx = (size_t)row * 3328 + col;
        float l1 = acc0[i][j][r], l2 = acc1[i][j][r];
        float corr = __sinf(PI2 * l1) * l1 + __sinf(2.f * PI2 * l2) * l2 * 0.5f;
        X[idx] = (bf16_t)(((float)X[idx] + sig * corr) * scale);
      }
    }
  }
}

// =====================================================================
// Flash attention v16 = EXACT revert to v13 (R7 build, 64.8 us, total
// 261.5 us). The v14/v15 KV-XCD remap halved FETCH (69.7->20.7 MB,
// mechanism verified) but produced an UNDIAGNOSED 4-10x HBM write
// amplification (WRITE 8.2->38.7->79 MB; not RMW — FETCH stayed flat)
// that cost +33-40 us. Abandoned per the pre-committed falsifier;
// needs TCC write-path counters to resolve. v13 = v11 data path +
// counted-vmcnt barrier (T4).
// =====================================================================
__global__ __launch_bounds__(256, 2) void flash_attn(const bf16_t* __restrict__ qkv,
                                                     bf16_t* __restrict__ aout) {
  constexpr int LD = 3328, SEQ = 2048;
  const int qb = blockIdx.x, bh = blockIdx.y;
  const int b = bh >> 4, h = bh & 15;
  const size_t base = (size_t)b * SEQ * LD + h * 64;
  const bf16_t* Qg = qkv + base;
  const bf16_t* Kg = qkv + base + 1024;
  const bf16_t* Vg = qkv + base + 2048;

  __shared__ __align__(16) unsigned char smem[67584];
  bf16_t(*VT0)[136] = (bf16_t(*)[136])smem;            // V slot 0 (even tiles)
  bf16_t(*VT1)[136] = (bf16_t(*)[136])(smem + 17408);  // V slot 1 (odd tiles)
  bf16_t* Kl0 = (bf16_t*)(smem + 34816);               // K slot 0 [128][64] swz
  bf16_t* Kl1 = (bf16_t*)(smem + 51200);               // K slot 1
  float* LDSo = (float*)smem;                // [256][24] f32, epilogue
  float* Lred = (float*)(smem + 24576);      // [1024] f32, epilogue
  float* invL = (float*)(smem + 28672);      // [128] f32, epilogue

  const int t = threadIdx.x, w = t >> 6, lane = t & 63;
  const int kw = w >> 1, qw = w & 1;
  const int quad = lane >> 4, l16 = lane & 15;
  const int q0 = qb * 128;

  // ---- Q fragments direct from global ----
  bf16x8 qf[4][2];
  {
    const bf16_t* Qrow = Qg + (size_t)(q0 + qw * 64 + l16) * LD + quad * 8;
#pragma unroll
    for (int nf = 0; nf < 4; ++nf)
#pragma unroll
      for (int ks = 0; ks < 2; ++ks)
        qf[nf][ks] = *(const bf16x8*)(Qrow + (size_t)(nf * 16) * LD + ks * 32);
  }

  f32x4 o[4][4] = {};
  float l_part[4] = {0.f, 0.f, 0.f, 0.f};

  const int vg = t >> 3, vcb = (t & 7) * 8;
  // key-slot permutation (PV B-fragment order) ^ 3-bit row-XOR bank swizzle
  const int colb = (((vg >> 3) << 5) | ((vg & 3) << 3) | (((vg >> 2) & 1) << 2)) ^ ((t & 7) << 3);
  const bf16_t* Vbase = Vg + (size_t)(vg * 4) * LD + vcb;

  // K staging geometry: LDS byte o = c*4096 + w*1024 + lane*16 decodes to
  // row = c*32 + w*8 + (lane>>3), stored 16B-chunk = lane&7. Source chunk
  // for that slot = (lane&7) ^ (row&7) = (lane&7) ^ (lane>>3).
  const bf16_t* Kstg = Kg + (size_t)(w * 8 + (lane >> 3)) * LD + ((lane & 7) ^ (lane >> 3)) * 8;

  float4 vr[4];  // V stage regs, one tile in flight (only loop-carried VMEM regs)

  // ---- prologue: DMA K tile 0 into Kl0; stage V tile 0 into VT0;
  //      issue vr loads for tile 1 ----
  {
    bf16_t* dst = Kl0 + w * 512;
#pragma unroll
    for (int c = 0; c < 4; ++c)
      async_cp16(Kstg + (size_t)(c * 32) * LD, dst + c * 2048);
  }
#pragma unroll
  for (int kk = 0; kk < 4; ++kk)
    vr[kk] = *(const float4*)(Vbase + (size_t)kk * LD);
#pragma unroll
  for (int cc = 0; cc < 8; ++cc) {
    union { bf16_t h[4]; uint2 u; } pk;
#pragma unroll
    for (int kk = 0; kk < 4; ++kk) pk.h[kk] = ((const bf16_t*)&vr[kk])[cc];
    *(uint2*)&VT0[vcb + cc][colb] = pk.u;
  }
#pragma unroll
  for (int kk = 0; kk < 4; ++kk)
    vr[kk] = *(const float4*)(Vbase + (size_t)(128 + kk) * LD);
  __syncthreads();  // VT0 + Kl0 ready (vmcnt drained); vr loads in flight

  for (int k0 = 0; k0 < SEQ; k0 += 128) {
    const int cur = (k0 >> 7) & 1;
    bf16_t(*VTc)[136] = cur ? VT1 : VT0;
    bf16_t(*VTn)[136] = cur ? VT0 : VT1;
    const bf16_t* Kc = cur ? Kl1 : Kl0;

    // ---- DMA next K tile into the other slot (completes by next barrier) ----
    if (k0 + 128 < SEQ) {
      bf16_t* dst = (cur ? Kl0 : Kl1) + w * 512;
#pragma unroll
      for (int c = 0; c < 4; ++c)
        async_cp16(Kstg + (size_t)(k0 + 128 + c * 32) * LD, dst + c * 2048);
    }

    // ---- K fragments from LDS (swizzled read; conflict-free) ----
    bf16x8 kf[4][2];
#pragma unroll
    for (int jk = 0; jk < 4; ++jk) {
      int row = kw * 64 + jk * 16 + l16;
#pragma unroll
      for (int ks = 0; ks < 2; ++ks) {
        int ch = (ks * 4 + quad) ^ (l16 & 7);
        kf[jk][ks] = *(const bf16x8*)&Kc[row * 64 + ch * 8];
      }
    }

    // ---- QK^T ----
    f32x4 st[4][4] = {};
    __builtin_amdgcn_s_setprio(1);
#pragma unroll
    for (int ks = 0; ks < 2; ++ks)
#pragma unroll
      for (int jk = 0; jk < 4; ++jk)
#pragma unroll
        for (int nf = 0; nf < 4; ++nf)
          st[jk][nf] = __builtin_amdgcn_mfma_f32_16x16x32_bf16(kf[jk][ks], qf[nf][ks], st[jk][nf], 0, 0, 0);
    __builtin_amdgcn_s_setprio(0);

    // ---- softmax + pack to bf16 (B-fragment key order) ----
    bf16x8 Pp[2][4];
#pragma unroll
    for (int g = 0; g < 2; ++g)
#pragma unroll
      for (int nf = 0; nf < 4; ++nf) {
        union { bf16_t hh[8]; bf16x8 v; } ph;
#pragma unroll
        for (int b2 = 0; b2 < 2; ++b2)
#pragma unroll
          for (int r = 0; r < 4; ++r) {
            float p = exp2f(st[g * 2 + b2][nf][r]);
            l_part[nf] += p;
            ph.hh[b2 * 4 + r] = (bf16_t)p;
          }
        Pp[g][nf] = ph.v;
      }

    // ---- stage: repack vr (tile k0+128) -> VTn, issue V loads k0+256.
    //      ds_writes overlap the PV MFMAs below. ----
    if (k0 + 128 < SEQ) {
#pragma unroll
      for (int cc = 0; cc < 8; ++cc) {
        union { bf16_t h[4]; uint2 u; } pk;
#pragma unroll
        for (int kk = 0; kk < 4; ++kk) pk.h[kk] = ((const bf16_t*)&vr[kk])[cc];
        *(uint2*)&VTn[vcb + cc][colb] = pk.u;
      }
      if (k0 + 256 < SEQ) {
#pragma unroll
        for (int kk = 0; kk < 4; ++kk)
          vr[kk] = *(const float4*)(Vbase + (size_t)(k0 + 256 + kk) * LD);
      }
    }

    // ---- PV from VTc (written last iter; ready since barrier) ----
#pragma unroll
    for (int g = 0; g < 2; ++g) {
      bf16x8 vf[4];
#pragma unroll
      for (int jd = 0; jd < 4; ++jd) {
        int row = jd * 16 + l16;
        int col = (kw * 64 + g * 32 + quad * 8) ^ ((((row >> 3) & 7)) << 3);
        vf[jd] = *(const bf16x8*)&VTc[row][col];
      }
      __builtin_amdgcn_s_setprio(1);
#pragma unroll
      for (int jd = 0; jd < 4; ++jd)
#pragma unroll
        for (int nf = 0; nf < 4; ++nf)
          o[jd][nf] = __builtin_amdgcn_mfma_f32_16x16x32_bf16(vf[jd], Pp[g][nf], o[jd][nf], 0, 0, 0);
      __builtin_amdgcn_s_setprio(0);
    }

    // ---- counted-vmcnt barrier (T4): drain K-DMA (+ repack ds_writes
    // via lgkmcnt) but let the 4 vr loads stay in flight. vr are the 4
    // NEWEST vmem ops this iter (issued after the K-DMA), so vmcnt(4)
    // waits exactly for everything older. Tail iters without vr loads
    // fall back to a full drain so the last K-DMA is covered.
    __builtin_amdgcn_sched_barrier(0);
    if (k0 + 256 < SEQ)
      asm volatile("s_waitcnt vmcnt(4) lgkmcnt(0)" ::: "memory");
    else
      asm volatile("s_waitcnt vmcnt(0) lgkmcnt(0)" ::: "memory");
    __builtin_amdgcn_s_barrier();
    __builtin_amdgcn_sched_barrier(0);
  }

  // ---- epilogue: reduce l and O across kw/quad, divide, store aout ----
#pragma unroll
  for (int nf = 0; nf < 4; ++nf)
    Lred[((kw * 2 + qw) * 4 + quad) * 64 + nf * 16 + l16] = l_part[nf];
  __syncthreads();
  if (t < 128) {
    int qw2 = t >> 6, ql = t & 63;
    float s = 0.f;
#pragma unroll
    for (int kw2 = 0; kw2 < 2; ++kw2)
#pragma unroll
      for (int qd = 0; qd < 4; ++qd)
        s += Lred[((kw2 * 2 + qw2) * 4 + qd) * 64 + ql];
    invL[t] = 1.f / s;
  }
  __syncthreads();

  const int rq = t >> 1, rc0 = (t & 1) * 8;
#pragma unroll
  for (int jd = 0; jd < 4; ++jd) {
#pragma unroll
    for (int nf = 0; nf < 4; ++nf)
      *(f32x4*)&LDSo[(size_t)(kw * 128 + qw * 64 + nf * 16 + l16) * 24 + quad * 4] = o[jd][nf];
    __syncthreads();
    f32x4 a0 = *(const f32x4*)&LDSo[(size_t)rq * 24 + rc0];
    f32x4 a1 = *(const f32x4*)&LDSo[(size_t)(128 + rq) * 24 + rc0];
    f32x4 b0 = *(const f32x4*)&LDSo[(size_t)rq * 24 + rc0 + 4];
    f32x4 b1 = *(const f32x4*)&LDSo[(size_t)(128 + rq) * 24 + rc0 + 4];
    float iv = invL[rq];
    union { bf16_t h[8]; uint4 u; } pk;
#pragma unroll
    for (int r = 0; r < 4; ++r) {
      pk.h[r] = (bf16_t)((a0[r] + a1[r]) * iv);
      pk.h[4 + r] = (bf16_t)((b0[r] + b1[r]) * iv);
    }
    *(uint4*)&aout[(size_t)(b * SEQ + q0 + rq) * 1024 + h * 64 + jd * 16 + rc0] = pk.u;
    if (jd < 3) __syncthreads();
  }
}

// =====================================================================
// host launch
// =====================================================================
extern "C" void kernel_launch(void* const* d_in, const int* in_sizes, int n_in,
                              void* d_out, int out_size, void* d_ws, size_t ws_size,
                              hipStream_t stream) {
  const float* hs   = (const float*)d_in[0];
  const float* Wq   = (const float*)d_in[1];
  const float* bq   = (const float*)d_in[2];
  const float* Wk   = (const float*)d_in[3];
  const float* bk   = (const float*)d_in[4];
  const float* Wv   = (const float*)d_in[5];
  const float* bv   = (const float*)d_in[6];
  const float* Wo   = (const float*)d_in[7];
  const float* bo   = (const float*)d_in[8];
  const float* qta  = (const float*)d_in[9];
  const float* qtb  = (const float*)d_in[10];
  const float* kta  = (const float*)d_in[11];
  const float* ktb  = (const float*)d_in[12];
  const float* coup = (const float*)d_in[13];
  float* out = (float*)d_out;

  uint8_t* ws = (uint8_t*)d_ws;
  bf16_t* hsb   = (bf16_t*)(ws);              // dead after gemm_qkv -> aout
  bf16_t* aout  = (bf16_t*)(ws);              // flash output overlays hsb
  bf16_t* BtExt = (bf16_t*)(ws + 8388608);    // [3328][1024]
  bf16_t* WoT   = (bf16_t*)(ws + 16777216);   // 2 MB
  float*  biasN = (float*)(ws + 18874368);    // 16 KB
  bf16_t* qkv   = (bf16_t*)(ws + 18890752);   // [4096][3328] 27.3 MB
  bf16_t* Wqb   = (bf16_t*)(ws + 46153728);   // prep scratch
  bf16_t* Wkb   = (bf16_t*)(ws + 48250880);
  bf16_t* qtaT  = (bf16_t*)(ws + 50348032);
  bf16_t* ktaT  = (bf16_t*)(ws + 50610176);
  bf16_t* qtbT  = (bf16_t*)(ws + 50872320);
  bf16_t* ktbT  = (bf16_t*)(ws + 51134464);

  dim3 b256(256);

  prep<<<6684, b256, 0, stream>>>(hs, hsb, Wq, Wk, Wv, Wo, BtExt, WoT, Wqb, Wkb,
                                  qta, kta, qtaT, ktaT, qtb, ktb, qtbT, ktbT,
                                  bq, bk, bv, biasN);
  gemm_wta<<<dim3(8, 2, 2), b256, 0, stream>>>(qtaT, ktaT, Wqb, Wkb, BtExt);
  gemm_qkv<<<dim3(26, 32), b256, 0, stream>>>(hsb, BtExt, qkv, biasN);
  lin_torsion_fused<<<dim3(8, 32, 2), b256, 0, stream>>>(qtbT, ktbT, qkv, coup);
  flash_attn<<<dim3(16, 32), b256, 0, stream>>>(qkv, aout);
  gemm_out<<<dim3(8, 32), b256, 0, stream>>>(aout, WoT, out, bo);
}

// Round 11
// 257.459 us; speedup vs baseline: 1.1662x; 1.0169x over previous
//
#include <hip/hip_runtime.h>
#include <hip/hip_bf16.h>
#include <cstdint>
#include <cstddef>

typedef __bf16 bf16_t;
typedef __bf16 bf16x8 __attribute__((ext_vector_type(8)));
typedef float f32x4 __attribute__((ext_vector_type(4)));

static __device__ __forceinline__ void st_out(float* p, float v) { *p = v; }
static __device__ __forceinline__ void st_out(bf16_t* p, float v) { *p = (bf16_t)v; }

static __device__ __forceinline__ void async_cp16(const bf16_t* g, bf16_t* l) {
  __builtin_amdgcn_global_load_lds(
      (const __attribute__((address_space(1))) void*)g,
      (__attribute__((address_space(3))) void*)l, 16, 0, 0);
}

// =====================================================================
// prep: all setup work in ONE launch. 1D grid, block ranges:
// [0,2048) cvt hs | [2048,6144) W transposes | [6144,6400) ta^T
// [6400,6656) tb^T | [6656,6668) bias concat | [6668,6684) low bias
// =====================================================================
__global__ __launch_bounds__(256) void prep(const float* __restrict__ hs, bf16_t* __restrict__ hsb,
                                            const float* __restrict__ Wq, const float* __restrict__ Wk,
                                            const float* __restrict__ Wv, const float* __restrict__ Wo,
                                            bf16_t* __restrict__ BtExt, bf16_t* __restrict__ WoT,
                                            bf16_t* __restrict__ Wqb, bf16_t* __restrict__ Wkb,
                                            const float* __restrict__ qta, const float* __restrict__ kta,
                                            bf16_t* __restrict__ qtaT, bf16_t* __restrict__ ktaT,
                                            const float* __restrict__ qtb, const float* __restrict__ ktb,
                                            bf16_t* __restrict__ qtbT, bf16_t* __restrict__ ktbT,
                                            const float* __restrict__ bq, const float* __restrict__ bk,
                                            const float* __restrict__ bv, float* __restrict__ biasN) {
  __shared__ float tile[32][33];
  const int bid = blockIdx.x, t = threadIdx.x;
  const int tx = t & 31, ty = t >> 5;

  if (bid < 2048) {  // ---- cvt ----
    int i = (bid * 256 + t) * 8;
    float4 a = *(const float4*)(hs + i);
    float4 b = *(const float4*)(hs + i + 4);
    union { bf16_t h[8]; uint4 u; } p;
    p.h[0] = (bf16_t)a.x; p.h[1] = (bf16_t)a.y; p.h[2] = (bf16_t)a.z; p.h[3] = (bf16_t)a.w;
    p.h[4] = (bf16_t)b.x; p.h[5] = (bf16_t)b.y; p.h[6] = (bf16_t)b.z; p.h[7] = (bf16_t)b.w;
    *(uint4*)(hsb + i) = p.u;
  } else if (bid < 6144) {  // ---- weight transposes ----
    int r = bid - 2048, z = r >> 10, r10 = r & 1023;
    int bx = (r10 & 31) * 32, by = (r10 >> 5) * 32;
    const float* src = z == 0 ? Wq : z == 1 ? Wk : z == 2 ? Wv : Wo;
    bf16_t* dst = z == 3 ? WoT : BtExt + (size_t)z * 1048576;
    bf16_t* sd = z == 0 ? Wqb : z == 1 ? Wkb : nullptr;
#pragma unroll
    for (int i = 0; i < 4; ++i) {
      float v = src[(size_t)(by + ty + i * 8) * 1024 + bx + tx];
      tile[ty + i * 8][tx] = v;
      if (sd) sd[(size_t)(by + ty + i * 8) * 1024 + bx + tx] = (bf16_t)v;
    }
    __syncthreads();
#pragma unroll
    for (int i = 0; i < 4; ++i)
      dst[(size_t)(bx + ty + i * 8) * 1024 + by + tx] = (bf16_t)tile[tx][ty + i * 8];
  } else if (bid < 6400) {  // ---- ta: [1024][64] -> [64][1024] ----
    int r = bid - 6144, z = r >> 6, r6 = r & 63;
    int bx = (r6 & 1) * 32, by = (r6 >> 1) * 32;
    const float* src = ((z >> 1) ? kta : qta) + (size_t)(z & 1) * 65536;
    bf16_t* dst = ((z >> 1) ? ktaT : qtaT) + (size_t)(z & 1) * 65536;
#pragma unroll
    for (int i = 0; i < 4; ++i)
      tile[ty + i * 8][tx] = src[(size_t)(by + ty + i * 8) * 64 + bx + tx];
    __syncthreads();
#pragma unroll
    for (int i = 0; i < 4; ++i)
      dst[(size_t)(bx + ty + i * 8) * 1024 + by + tx] = (bf16_t)tile[tx][ty + i * 8];
  } else if (bid < 6656) {  // ---- tb: [64][1024] -> [1024][64] ----
    int r = bid - 6400, z = r >> 6, r6 = r & 63;
    int bx = (r6 & 31) * 32, by = (r6 >> 5) * 32;
    const float* src = ((z >> 1) ? ktb : qtb) + (size_t)(z & 1) * 65536;
    bf16_t* dst = ((z >> 1) ? ktbT : qtbT) + (size_t)(z & 1) * 65536;
#pragma unroll
    for (int i = 0; i < 4; ++i)
      tile[ty + i * 8][tx] = src[(size_t)(by + ty + i * 8) * 1024 + bx + tx];
    __syncthreads();
#pragma unroll
    for (int i = 0; i < 4; ++i)
      dst[(size_t)(bx + ty + i * 8) * 64 + by + tx] = (bf16_t)tile[tx][ty + i * 8];
  } else if (bid < 6668) {  // ---- bias concat ----
    int i = (bid - 6656) * 256 + t;
    biasN[i] = (i < 1024) ? bq[i] : (i < 2048 ? bk[i - 1024] : bv[i - 2048]);
  } else {  // ---- low bias: 16 blocks x 16 j-outputs, 16 h-lanes each ----
    int B = bid - 6668;                 // 0..15
    int j = B * 16 + (t >> 4);          // output index 0..255
    int hoff = t & 15;
    const float* b = (j < 128) ? bq : bk;
    const float* ta = ((j < 128) ? qta : kta) + (size_t)((j >> 6) & 1) * 65536;
    int rr = j & 63;
    float s = 0.f;
#pragma unroll 4
    for (int i = 0; i < 64; ++i) {
      int h = hoff + i * 16;
      s += b[h] * ta[(size_t)h * 64 + rr];
    }
    // reduce across the 16 h-lanes (xor widths 1,2,4,8 stay in-wave)
#pragma unroll
    for (int m = 8; m >= 1; m >>= 1) s += __shfl_xor(s, m, 64);
    if (hoff == 0) biasN[3072 + j] = s;
  }
}

// =====================================================================
// 128x128 BK=64 async GEMM core: m97 fragment layout, 64-wide K-steps
// (half the barrier pairs). Bank swizzle via pre-swizzled global SOURCE
// + swizzled read (rule #21), chunk ^= row&7; DMA dest stays linear.
// =====================================================================
template <typename OutT>
static __device__ __forceinline__ void gemm_core_bk64(const bf16_t* __restrict__ A, int lda,
                                                      const bf16_t* __restrict__ Bt, int ldb,
                                                      OutT* __restrict__ C, int ldc,
                                                      const float* __restrict__ bias, int K,
                                                      int bx, int by) {
  __shared__ bf16_t As[128][64];
  __shared__ bf16_t Bs[128][64];
  const int m0 = by * 128, n0 = bx * 128;
  const int t = threadIdx.x, w = t >> 6, lane = t & 63;
  const int wm = (w >> 1) * 64, wn = (w & 1) * 64;
  const int quad = lane >> 4, l16 = lane & 15;
  const int sra = lane >> 3;            // row 0..7 within an 8-row group
  const int sch = lane & 7;             // dest 16B chunk 0..7
  // source col chunk = sch ^ (row&7): LDS[row][q] = global[row][q^(row&7)]
  const bf16_t* Ag = A + (size_t)(m0 + w * 32 + sra) * lda + (sch ^ sra) * 8;
  const bf16_t* Bg = Bt + (size_t)(n0 + w * 32 + sra) * ldb + (sch ^ sra) * 8;
  bf16_t* la = &As[0][0] + w * 2048;    // wave-uniform; lane offset = lane*16B
  bf16_t* lb = &Bs[0][0] + w * 2048;

  f32x4 acc[4][4] = {};
  for (int k0 = 0; k0 < K; k0 += 64) {
    __syncthreads();
#pragma unroll
    for (int c = 0; c < 4; ++c)
      async_cp16(Ag + k0 + (size_t)(c * 8) * lda, la + c * 512);
#pragma unroll
    for (int c = 0; c < 4; ++c)
      async_cp16(Bg + k0 + (size_t)(c * 8) * ldb, lb + c * 512);
    __syncthreads();
#pragma unroll
    for (int ks = 0; ks < 2; ++ks) {
      bf16x8 af[4], bfr[4];
#pragma unroll
      for (int i = 0; i < 4; ++i)
        af[i] = *(const bf16x8*)&As[wm + i * 16 + l16][((ks * 4 + quad) ^ (l16 & 7)) * 8];
#pragma unroll
      for (int j = 0; j < 4; ++j)
        bfr[j] = *(const bf16x8*)&Bs[wn + j * 16 + l16][((ks * 4 + quad) ^ (l16 & 7)) * 8];
#pragma unroll
      for (int i = 0; i < 4; ++i)
#pragma unroll
        for (int j = 0; j < 4; ++j)
          acc[i][j] = __builtin_amdgcn_mfma_f32_16x16x32_bf16(af[i], bfr[j], acc[i][j], 0, 0, 0);
    }
  }
#pragma unroll
  for (int i = 0; i < 4; ++i) {
    int row = m0 + wm + i * 16 + quad * 4;
#pragma unroll
    for (int j = 0; j < 4; ++j) {
      int col = n0 + wn + j * 16 + l16;
      float bv = bias ? bias[col] : 0.f;
#pragma unroll
      for (int r = 0; r < 4; ++r)
        st_out(&C[(size_t)(row + r) * ldc + col], acc[i][j][r] + bv);
    }
  }
}

// 64x128 BK=32 variant (gemm_wta split-K uses it with K=256 chunks)
template <typename OutT>
static __device__ __forceinline__ void gemm_core_async64(const bf16_t* __restrict__ A, int lda,
                                                         const bf16_t* __restrict__ Bt, int ldb,
                                                         OutT* __restrict__ C, int ldc,
                                                         const float* __restrict__ bias, int K,
                                                         int bx, int by) {
  __shared__ bf16_t As[64][32];
  __shared__ bf16_t Bs[128][32];
  const int m0 = by * 64, n0 = bx * 128;
  const int t = threadIdx.x, w = t >> 6, lane = t & 63;
  const int wm = (w >> 1) * 32, wn = (w & 1) * 64;
  const int quad = lane >> 4, l16 = lane & 15;
  const int sra = lane >> 2, sca = (lane & 3) * 8;
  const bf16_t* Ag0 = A + (size_t)(m0 + w * 16 + sra) * lda + sca;
  const bf16_t* Bg0 = Bt + (size_t)(n0 + w * 16 + sra) * ldb + sca;
  const bf16_t* Bg1 = Bt + (size_t)(n0 + 64 + w * 16 + sra) * ldb + sca;
  bf16_t* la0 = &As[0][0] + w * 512;
  bf16_t* lb0 = &Bs[0][0] + w * 512;
  bf16_t* lb1 = &Bs[0][0] + 2048 + w * 512;

  f32x4 acc[2][4] = {};
  for (int k0 = 0; k0 < K; k0 += 32) {
    __syncthreads();
    async_cp16(Ag0 + k0, la0);
    async_cp16(Bg0 + k0, lb0);
    async_cp16(Bg1 + k0, lb1);
    __syncthreads();
    bf16x8 af[2], bfr[4];
#pragma unroll
    for (int i = 0; i < 2; ++i)
      af[i] = *(const bf16x8*)&As[wm + i * 16 + l16][quad * 8];
#pragma unroll
    for (int j = 0; j < 4; ++j)
      bfr[j] = *(const bf16x8*)&Bs[wn + j * 16 + l16][quad * 8];
#pragma unroll
    for (int i = 0; i < 2; ++i)
#pragma unroll
      for (int j = 0; j < 4; ++j)
        acc[i][j] = __builtin_amdgcn_mfma_f32_16x16x32_bf16(af[i], bfr[j], acc[i][j], 0, 0, 0);
  }
#pragma unroll
  for (int i = 0; i < 2; ++i) {
    int row = m0 + wm + i * 16 + quad * 4;
#pragma unroll
    for (int j = 0; j < 4; ++j) {
      int col = n0 + wn + j * 16 + l16;
      float bv = bias ? bias[col] : 0.f;
#pragma unroll
      for (int r = 0; r < 4; ++r)
        st_out(&C[(size_t)(row + r) * ldc + col], acc[i][j][r] + bv);
    }
  }
}

// XCD-aware swizzle (T1): dispatch id d runs on XCD d%8; remap so each
// XCD owns a contiguous tile range. Requires nwg % 8 == 0 (bijective).
__global__ __launch_bounds__(256) void gemm_qkv(const bf16_t* __restrict__ A,
                                                const bf16_t* __restrict__ Bt,
                                                bf16_t* __restrict__ C,
                                                const float* __restrict__ biasN) {
  int id = blockIdx.y * 26 + blockIdx.x;          // 832 = 8 * 104
  int nid = (id & 7) * 104 + (id >> 3);
  gemm_core_bk64<bf16_t>(A, 1024, Bt, 1024, C, 3328, biasN, 1024, nid % 26, nid / 26);
}

__global__ __launch_bounds__(256) void gemm_out(const bf16_t* __restrict__ A,
                                                const bf16_t* __restrict__ Bt,
                                                float* __restrict__ C,
                                                const float* __restrict__ bo) {
  int id = blockIdx.y * 8 + blockIdx.x;           // 256 = 8 * 32
  int nid = (id & 7) * 32 + (id >> 3);
  gemm_core_bk64<float>(A, 1024, Bt, 1024, C, 1024, bo, 1024, nid & 7, nid >> 3);
}

// =====================================================================
// gemm_wta split-K4: old version ran 32 blocks (1 block/CU, no latency
// co-residency) over K=1024 serially. Split K into 4x256 chunks -> 128
// blocks writing f32 partials into the (currently dead) qkv workspace
// region; wta_combine sums 4 partials + cvt->bf16 into BtExt before
// gemm_qkv overwrites the region. Sum order change only (f32 all the
// way); output bit-identical modulo add order.
// =====================================================================
__global__ __launch_bounds__(256) void gemm_wta(const bf16_t* __restrict__ qtaT,
                                                const bf16_t* __restrict__ ktaT,
                                                const bf16_t* __restrict__ Wqb,
                                                const bf16_t* __restrict__ Wkb,
                                                float* __restrict__ P) {
  int zz = blockIdx.z;                 // 0..7: z = zz>>2, kc = zz&3
  int z = zz >> 2, kc = zz & 3;
  const bf16_t* A = (z ? ktaT : qtaT) + kc * 256;
  const bf16_t* B = (z ? Wkb : Wqb) + kc * 256;
  gemm_core_async64<float>(A, 1024, B, 1024,
                           P + (size_t)zz * 131072, 1024,
                           nullptr, 256, blockIdx.x, blockIdx.y);
}

__global__ __launch_bounds__(256) void wta_combine(const float* __restrict__ P,
                                                   bf16_t* __restrict__ BtExt) {
  int i = blockIdx.x * 256 + threadIdx.x;   // [0, 262144)
  int z = i >> 17;                          // 0..1
  int off = i & 131071;                     // row*1024 + col, row in [0,128)
  float s = (P[(size_t)(z * 4 + 0) * 131072 + off] + P[(size_t)(z * 4 + 1) * 131072 + off]) +
            (P[(size_t)(z * 4 + 2) * 131072 + off] + P[(size_t)(z * 4 + 3) * 131072 + off]);
  BtExt[(size_t)(3072 + z * 128) * 1024 + off] = (bf16_t)s;
}

// =====================================================================
// fused torsion + q pre-scale by log2(e)/8
// =====================================================================
__global__ __launch_bounds__(256) void lin_torsion_fused(const bf16_t* __restrict__ qtbT,
                                                         const bf16_t* __restrict__ ktbT,
                                                         bf16_t* __restrict__ qkv,
                                                         const float* __restrict__ coupling) {
  __shared__ bf16_t As[128][136];
  __shared__ bf16_t Bs0[128][72];
  __shared__ bf16_t Bs1[128][72];
  const int z = blockIdx.z;
  const bf16_t* Low = qkv + 3072 + z * 128;
  const bf16_t* Tb = z ? ktbT : qtbT;
  bf16_t* X = qkv + z * 1024;

  const int m0 = blockIdx.y * 128, n0 = blockIdx.x * 128;
  const int t = threadIdx.x, w = t >> 6, lane = t & 63;
  const int wm = (w >> 1) * 64, wn = (w & 1) * 64;
  const int quad = lane >> 4, l16 = lane & 15;

  {
    const int sr = t >> 1, sc = (t & 1) * 64;
    const bf16_t* Ag = Low + (size_t)(m0 + sr) * 3328 + sc;
#pragma unroll
    for (int i = 0; i < 8; ++i)
      *(float4*)&As[sr][sc + 8 * i] = *(const float4*)(Ag + 8 * i);
    const int br = t >> 1, bc = (t & 1) * 32;
    const bf16_t* Bg0 = Tb + (size_t)(n0 + br) * 64 + bc;
    const bf16_t* Bg1 = Bg0 + 65536;
#pragma unroll
    for (int i = 0; i < 4; ++i) {
      *(float4*)&Bs0[br][bc + 8 * i] = *(const float4*)(Bg0 + 8 * i);
      *(float4*)&Bs1[br][bc + 8 * i] = *(const float4*)(Bg1 + 8 * i);
    }
  }
  __syncthreads();

  f32x4 acc0[4][4] = {}, acc1[4][4] = {};
#pragma unroll
  for (int ks = 0; ks < 2; ++ks) {
    bf16x8 a0[4], a1[4];
#pragma unroll
    for (int i = 0; i < 4; ++i) {
      a0[i] = *(const bf16x8*)&As[wm + i * 16 + l16][ks * 32 + quad * 8];
      a1[i] = *(const bf16x8*)&As[wm + i * 16 + l16][64 + ks * 32 + quad * 8];
    }
#pragma unroll
    for (int j = 0; j < 4; ++j) {
      bf16x8 b0 = *(const bf16x8*)&Bs0[wn + j * 16 + l16][ks * 32 + quad * 8];
      bf16x8 b1 = *(const bf16x8*)&Bs1[wn + j * 16 + l16][ks * 32 + quad * 8];
#pragma unroll
      for (int i = 0; i < 4; ++i) {
        acc0[i][j] = __builtin_amdgcn_mfma_f32_16x16x32_bf16(a0[i], b0, acc0[i][j], 0, 0, 0);
        acc1[i][j] = __builtin_amdgcn_mfma_f32_16x16x32_bf16(a1[i], b1, acc1[i][j], 0, 0, 0);
      }
    }
  }

  const float PI2 = 6.283185307179586f;
  const float sig = 1.f / (1.f + __expf(-coupling[0]));
  const float scale = z ? 1.f : 0.1803368801111204f;
#pragma unroll
  for (int i = 0; i < 4; ++i) {
#pragma unroll
    for (int j = 0; j < 4; ++j) {
#pragma unroll
      for (int r = 0; r < 4; ++r) {
        int row = m0 + wm + i * 16 + quad * 4 + r;
        int col = n0 + wn + j * 16 + l16;
        size_t idx = (size_t)row * 3328 + col;
        float l1 = acc0[i][j][r], l2 = acc1[i][j][r];
        float corr = __sinf(PI2 * l1) * l1 + __sinf(2.f * PI2 * l2) * l2 * 0.5f;
        X[idx] = (bf16_t)(((float)X[idx] + sig * corr) * scale);
      }
    }
  }
}

// =====================================================================
// Flash attention v17 = v13 + T12 packing primitive in the softmax:
// the 64 scalar (bf16_t) casts + union byte-inserts per iter (~4-6
// VALU inst each under hipcc) become 32 v_cvt_pk_bf16_f32 (1 inst per
// f32 pair, writes the packed word directly). l adds restructured as
// pairwise trees (chain 16 -> 4 per nf-iter). No volatile / no sched
// pins so the scheduler stays free (avoids m240's pinning regression).
// cvt_pk is RNE like the scalar cast (m214v22 refcheck'd) -> absmax
// expected unchanged. Everything else identical to v13 (64.4 us).
// =====================================================================
__global__ __launch_bounds__(256, 2) void flash_attn(const bf16_t* __restrict__ qkv,
                                                     bf16_t* __restrict__ aout) {
  constexpr int LD = 3328, SEQ = 2048;
  const int qb = blockIdx.x, bh = blockIdx.y;
  const int b = bh >> 4, h = bh & 15;
  const size_t base = (size_t)b * SEQ * LD + h * 64;
  const bf16_t* Qg = qkv + base;
  const bf16_t* Kg = qkv + base + 1024;
  const bf16_t* Vg = qkv + base + 2048;

  __shared__ __align__(16) unsigned char smem[67584];
  bf16_t(*VT0)[136] = (bf16_t(*)[136])smem;            // V slot 0 (even tiles)
  bf16_t(*VT1)[136] = (bf16_t(*)[136])(smem + 17408);  // V slot 1 (odd tiles)
  bf16_t* Kl0 = (bf16_t*)(smem + 34816);               // K slot 0 [128][64] swz
  bf16_t* Kl1 = (bf16_t*)(smem + 51200);               // K slot 1
  float* LDSo = (float*)smem;                // [256][24] f32, epilogue
  float* Lred = (float*)(smem + 24576);      // [1024] f32, epilogue
  float* invL = (float*)(smem + 28672);      // [128] f32, epilogue

  const int t = threadIdx.x, w = t >> 6, lane = t & 63;
  const int kw = w >> 1, qw = w & 1;
  const int quad = lane >> 4, l16 = lane & 15;
  const int q0 = qb * 128;

  // ---- Q fragments direct from global ----
  bf16x8 qf[4][2];
  {
    const bf16_t* Qrow = Qg + (size_t)(q0 + qw * 64 + l16) * LD + quad * 8;
#pragma unroll
    for (int nf = 0; nf < 4; ++nf)
#pragma unroll
      for (int ks = 0; ks < 2; ++ks)
        qf[nf][ks] = *(const bf16x8*)(Qrow + (size_t)(nf * 16) * LD + ks * 32);
  }

  f32x4 o[4][4] = {};
  float l_part[4] = {0.f, 0.f, 0.f, 0.f};

  const int vg = t >> 3, vcb = (t & 7) * 8;
  // key-slot permutation (PV B-fragment order) ^ 3-bit row-XOR bank swizzle
  const int colb = (((vg >> 3) << 5) | ((vg & 3) << 3) | (((vg >> 2) & 1) << 2)) ^ ((t & 7) << 3);
  const bf16_t* Vbase = Vg + (size_t)(vg * 4) * LD + vcb;

  // K staging geometry: LDS byte o = c*4096 + w*1024 + lane*16 decodes to
  // row = c*32 + w*8 + (lane>>3), stored 16B-chunk = lane&7. Source chunk
  // for that slot = (lane&7) ^ (row&7) = (lane&7) ^ (lane>>3).
  const bf16_t* Kstg = Kg + (size_t)(w * 8 + (lane >> 3)) * LD + ((lane & 7) ^ (lane >> 3)) * 8;

  float4 vr[4];  // V stage regs, one tile in flight (only loop-carried VMEM regs)

  // ---- prologue: DMA K tile 0 into Kl0; stage V tile 0 into VT0;
  //      issue vr loads for tile 1 ----
  {
    bf16_t* dst = Kl0 + w * 512;
#pragma unroll
    for (int c = 0; c < 4; ++c)
      async_cp16(Kstg + (size_t)(c * 32) * LD, dst + c * 2048);
  }
#pragma unroll
  for (int kk = 0; kk < 4; ++kk)
    vr[kk] = *(const float4*)(Vbase + (size_t)kk * LD);
#pragma unroll
  for (int cc = 0; cc < 8; ++cc) {
    union { bf16_t h[4]; uint2 u; } pk;
#pragma unroll
    for (int kk = 0; kk < 4; ++kk) pk.h[kk] = ((const bf16_t*)&vr[kk])[cc];
    *(uint2*)&VT0[vcb + cc][colb] = pk.u;
  }
#pragma unroll
  for (int kk = 0; kk < 4; ++kk)
    vr[kk] = *(const float4*)(Vbase + (size_t)(128 + kk) * LD);
  __syncthreads();  // VT0 + Kl0 ready (vmcnt drained); vr loads in flight

  for (int k0 = 0; k0 < SEQ; k0 += 128) {
    const int cur = (k0 >> 7) & 1;
    bf16_t(*VTc)[136] = cur ? VT1 : VT0;
    bf16_t(*VTn)[136] = cur ? VT0 : VT1;
    const bf16_t* Kc = cur ? Kl1 : Kl0;

    // ---- DMA next K tile into the other slot (completes by next barrier) ----
    if (k0 + 128 < SEQ) {
      bf16_t* dst = (cur ? Kl0 : Kl1) + w * 512;
#pragma unroll
      for (int c = 0; c < 4; ++c)
        async_cp16(Kstg + (size_t)(k0 + 128 + c * 32) * LD, dst + c * 2048);
    }

    // ---- K fragments from LDS (swizzled read; conflict-free) ----
    bf16x8 kf[4][2];
#pragma unroll
    for (int jk = 0; jk < 4; ++jk) {
      int row = kw * 64 + jk * 16 + l16;
#pragma unroll
      for (int ks = 0; ks < 2; ++ks) {
        int ch = (ks * 4 + quad) ^ (l16 & 7);
        kf[jk][ks] = *(const bf16x8*)&Kc[row * 64 + ch * 8];
      }
    }

    // ---- QK^T ----
    f32x4 st[4][4] = {};
    __builtin_amdgcn_s_setprio(1);
#pragma unroll
    for (int ks = 0; ks < 2; ++ks)
#pragma unroll
      for (int jk = 0; jk < 4; ++jk)
#pragma unroll
        for (int nf = 0; nf < 4; ++nf)
          st[jk][nf] = __builtin_amdgcn_mfma_f32_16x16x32_bf16(kf[jk][ks], qf[nf][ks], st[jk][nf], 0, 0, 0);
    __builtin_amdgcn_s_setprio(0);

    // ---- softmax: exp2 + packed bf16 cvt (T12 primitive) ----
    bf16x8 Pp[2][4];
#pragma unroll
    for (int g = 0; g < 2; ++g)
#pragma unroll
      for (int nf = 0; nf < 4; ++nf) {
        union { uint32_t wd[4]; bf16x8 v; } ph;
#pragma unroll
        for (int b2 = 0; b2 < 2; ++b2) {
          float p0 = exp2f(st[g * 2 + b2][nf][0]);
          float p1 = exp2f(st[g * 2 + b2][nf][1]);
          float p2 = exp2f(st[g * 2 + b2][nf][2]);
          float p3 = exp2f(st[g * 2 + b2][nf][3]);
          l_part[nf] += (p0 + p1) + (p2 + p3);
          uint32_t w0, w1;
          asm("v_cvt_pk_bf16_f32 %0, %1, %2" : "=v"(w0) : "v"(p0), "v"(p1));
          asm("v_cvt_pk_bf16_f32 %0, %1, %2" : "=v"(w1) : "v"(p2), "v"(p3));
          ph.wd[b2 * 2 + 0] = w0;   // hh[b2*4+0..1]
          ph.wd[b2 * 2 + 1] = w1;   // hh[b2*4+2..3]
        }
        Pp[g][nf] = ph.v;
      }

    // ---- stage: repack vr (tile k0+128) -> VTn, issue V loads k0+256.
    //      ds_writes overlap the PV MFMAs below. ----
    if (k0 + 128 < SEQ) {
#pragma unroll
      for (int cc = 0; cc < 8; ++cc) {
        union { bf16_t h[4]; uint2 u; } pk;
#pragma unroll
        for (int kk = 0; kk < 4; ++kk) pk.h[kk] = ((const bf16_t*)&vr[kk])[cc];
        *(uint2*)&VTn[vcb + cc][colb] = pk.u;
      }
      if (k0 + 256 < SEQ) {
#pragma unroll
        for (int kk = 0; kk < 4; ++kk)
          vr[kk] = *(const float4*)(Vbase + (size_t)(k0 + 256 + kk) * LD);
      }
    }

    // ---- PV from VTc (written last iter; ready since barrier) ----
#pragma unroll
    for (int g = 0; g < 2; ++g) {
      bf16x8 vf[4];
#pragma unroll
      for (int jd = 0; jd < 4; ++jd) {
        int row = jd * 16 + l16;
        int col = (kw * 64 + g * 32 + quad * 8) ^ ((((row >> 3) & 7)) << 3);
        vf[jd] = *(const bf16x8*)&VTc[row][col];
      }
      __builtin_amdgcn_s_setprio(1);
#pragma unroll
      for (int jd = 0; jd < 4; ++jd)
#pragma unroll
        for (int nf = 0; nf < 4; ++nf)
          o[jd][nf] = __builtin_amdgcn_mfma_f32_16x16x32_bf16(vf[jd], Pp[g][nf], o[jd][nf], 0, 0, 0);
      __builtin_amdgcn_s_setprio(0);
    }

    // ---- counted-vmcnt barrier (T4): drain K-DMA (+ repack ds_writes
    // via lgkmcnt) but let the 4 vr loads stay in flight. vr are the 4
    // NEWEST vmem ops this iter (issued after the K-DMA), so vmcnt(4)
    // waits exactly for everything older. Tail iters without vr loads
    // fall back to a full drain so the last K-DMA is covered.
    __builtin_amdgcn_sched_barrier(0);
    if (k0 + 256 < SEQ)
      asm volatile("s_waitcnt vmcnt(4) lgkmcnt(0)" ::: "memory");
    else
      asm volatile("s_waitcnt vmcnt(0) lgkmcnt(0)" ::: "memory");
    __builtin_amdgcn_s_barrier();
    __builtin_amdgcn_sched_barrier(0);
  }

  // ---- epilogue: reduce l and O across kw/quad, divide, store aout ----
#pragma unroll
  for (int nf = 0; nf < 4; ++nf)
    Lred[((kw * 2 + qw) * 4 + quad) * 64 + nf * 16 + l16] = l_part[nf];
  __syncthreads();
  if (t < 128) {
    int qw2 = t >> 6, ql = t & 63;
    float s = 0.f;
#pragma unroll
    for (int kw2 = 0; kw2 < 2; ++kw2)
#pragma unroll
      for (int qd = 0; qd < 4; ++qd)
        s += Lred[((kw2 * 2 + qw2) * 4 + qd) * 64 + ql];
    invL[t] = 1.f / s;
  }
  __syncthreads();

  const int rq = t >> 1, rc0 = (t & 1) * 8;
#pragma unroll
  for (int jd = 0; jd < 4; ++jd) {
#pragma unroll
    for (int nf = 0; nf < 4; ++nf)
      *(f32x4*)&LDSo[(size_t)(kw * 128 + qw * 64 + nf * 16 + l16) * 24 + quad * 4] = o[jd][nf];
    __syncthreads();
    f32x4 a0 = *(const f32x4*)&LDSo[(size_t)rq * 24 + rc0];
    f32x4 a1 = *(const f32x4*)&LDSo[(size_t)(128 + rq) * 24 + rc0];
    f32x4 b0 = *(const f32x4*)&LDSo[(size_t)rq * 24 + rc0 + 4];
    f32x4 b1 = *(const f32x4*)&LDSo[(size_t)(128 + rq) * 24 + rc0 + 4];
    float iv = invL[rq];
    union { bf16_t h[8]; uint4 u; } pk;
#pragma unroll
    for (int r = 0; r < 4; ++r) {
      pk.h[r] = (bf16_t)((a0[r] + a1[r]) * iv);
      pk.h[4 + r] = (bf16_t)((b0[r] + b1[r]) * iv);
    }
    *(uint4*)&aout[(size_t)(b * SEQ + q0 + rq) * 1024 + h * 64 + jd * 16 + rc0] = pk.u;
    if (jd < 3) __syncthreads();
  }
}

// =====================================================================
// host launch
// =====================================================================
extern "C" void kernel_launch(void* const* d_in, const int* in_sizes, int n_in,
                              void* d_out, int out_size, void* d_ws, size_t ws_size,
                              hipStream_t stream) {
  const float* hs   = (const float*)d_in[0];
  const float* Wq   = (const float*)d_in[1];
  const float* bq   = (const float*)d_in[2];
  const float* Wk   = (const float*)d_in[3];
  const float* bk   = (const float*)d_in[4];
  const float* Wv   = (const float*)d_in[5];
  const float* bv   = (const float*)d_in[6];
  const float* Wo   = (const float*)d_in[7];
  const float* bo   = (const float*)d_in[8];
  const float* qta  = (const float*)d_in[9];
  const float* qtb  = (const float*)d_in[10];
  const float* kta  = (const float*)d_in[11];
  const float* ktb  = (const float*)d_in[12];
  const float* coup = (const float*)d_in[13];
  float* out = (float*)d_out;

  uint8_t* ws = (uint8_t*)d_ws;
  bf16_t* hsb   = (bf16_t*)(ws);              // dead after gemm_qkv -> aout
  bf16_t* aout  = (bf16_t*)(ws);              // flash output overlays hsb
  bf16_t* BtExt = (bf16_t*)(ws + 8388608);    // [3328][1024]
  bf16_t* WoT   = (bf16_t*)(ws + 16777216);   // 2 MB
  float*  biasN = (float*)(ws + 18874368);    // 16 KB
  bf16_t* qkv   = (bf16_t*)(ws + 18890752);   // [4096][3328] 27.3 MB
  float*  wtaP  = (float*)(ws + 18890752);    // 4 MB wta partials; dead
                                              // before gemm_qkv writes qkv
  bf16_t* Wqb   = (bf16_t*)(ws + 46153728);   // prep scratch
  bf16_t* Wkb   = (bf16_t*)(ws + 48250880);
  bf16_t* qtaT  = (bf16_t*)(ws + 50348032);
  bf16_t* ktaT  = (bf16_t*)(ws + 50610176);
  bf16_t* qtbT  = (bf16_t*)(ws + 50872320);
  bf16_t* ktbT  = (bf16_t*)(ws + 51134464);

  dim3 b256(256);

  prep<<<6684, b256, 0, stream>>>(hs, hsb, Wq, Wk, Wv, Wo, BtExt, WoT, Wqb, Wkb,
                                  qta, kta, qtaT, ktaT, qtb, ktb, qtbT, ktbT,
                                  bq, bk, bv, biasN);
  gemm_wta<<<dim3(8, 2, 8), b256, 0, stream>>>(qtaT, ktaT, Wqb, Wkb, wtaP);
  wta_combine<<<1024, b256, 0, stream>>>(wtaP, BtExt);
  gemm_qkv<<<dim3(26, 32), b256, 0, stream>>>(hsb, BtExt, qkv, biasN);
  lin_torsion_fused<<<dim3(8, 32, 2), b256, 0, stream>>>(qtbT, ktbT, qkv, coup);
  flash_attn<<<dim3(16, 32), b256, 0, stream>>>(qkv, aout);
  gemm_out<<<dim3(8, 32), b256, 0, stream>>>(aout, WoT, out, bo);
}

// Round 12
// 253.958 us; speedup vs baseline: 1.1823x; 1.0138x over previous
//
#include <hip/hip_runtime.h>
#include <hip/hip_bf16.h>
#include <cstdint>
#include <cstddef>

typedef __bf16 bf16_t;
typedef __bf16 bf16x8 __attribute__((ext_vector_type(8)));
typedef float f32x4 __attribute__((ext_vector_type(4)));

static __device__ __forceinline__ void st_out(float* p, float v) { *p = v; }
static __device__ __forceinline__ void st_out(bf16_t* p, float v) { *p = (bf16_t)v; }

static __device__ __forceinline__ void async_cp16(const bf16_t* g, bf16_t* l) {
  __builtin_amdgcn_global_load_lds(
      (const __attribute__((address_space(1))) void*)g,
      (__attribute__((address_space(3))) void*)l, 16, 0, 0);
}

// =====================================================================
// prep: all setup work in ONE launch. 1D grid, block ranges:
// [0,2048) cvt hs | [2048,6144) W transposes | [6144,6400) ta^T
// [6400,6656) tb^T | [6656,6668) bias concat | [6668,6684) low bias
// =====================================================================
__global__ __launch_bounds__(256) void prep(const float* __restrict__ hs, bf16_t* __restrict__ hsb,
                                            const float* __restrict__ Wq, const float* __restrict__ Wk,
                                            const float* __restrict__ Wv, const float* __restrict__ Wo,
                                            bf16_t* __restrict__ BtExt, bf16_t* __restrict__ WoT,
                                            bf16_t* __restrict__ Wqb, bf16_t* __restrict__ Wkb,
                                            const float* __restrict__ qta, const float* __restrict__ kta,
                                            bf16_t* __restrict__ qtaT, bf16_t* __restrict__ ktaT,
                                            const float* __restrict__ qtb, const float* __restrict__ ktb,
                                            bf16_t* __restrict__ qtbT, bf16_t* __restrict__ ktbT,
                                            const float* __restrict__ bq, const float* __restrict__ bk,
                                            const float* __restrict__ bv, float* __restrict__ biasN) {
  __shared__ float tile[32][33];
  const int bid = blockIdx.x, t = threadIdx.x;
  const int tx = t & 31, ty = t >> 5;

  if (bid < 2048) {  // ---- cvt ----
    int i = (bid * 256 + t) * 8;
    float4 a = *(const float4*)(hs + i);
    float4 b = *(const float4*)(hs + i + 4);
    union { bf16_t h[8]; uint4 u; } p;
    p.h[0] = (bf16_t)a.x; p.h[1] = (bf16_t)a.y; p.h[2] = (bf16_t)a.z; p.h[3] = (bf16_t)a.w;
    p.h[4] = (bf16_t)b.x; p.h[5] = (bf16_t)b.y; p.h[6] = (bf16_t)b.z; p.h[7] = (bf16_t)b.w;
    *(uint4*)(hsb + i) = p.u;
  } else if (bid < 6144) {  // ---- weight transposes ----
    int r = bid - 2048, z = r >> 10, r10 = r & 1023;
    int bx = (r10 & 31) * 32, by = (r10 >> 5) * 32;
    const float* src = z == 0 ? Wq : z == 1 ? Wk : z == 2 ? Wv : Wo;
    bf16_t* dst = z == 3 ? WoT : BtExt + (size_t)z * 1048576;
    bf16_t* sd = z == 0 ? Wqb : z == 1 ? Wkb : nullptr;
#pragma unroll
    for (int i = 0; i < 4; ++i) {
      float v = src[(size_t)(by + ty + i * 8) * 1024 + bx + tx];
      tile[ty + i * 8][tx] = v;
      if (sd) sd[(size_t)(by + ty + i * 8) * 1024 + bx + tx] = (bf16_t)v;
    }
    __syncthreads();
#pragma unroll
    for (int i = 0; i < 4; ++i)
      dst[(size_t)(bx + ty + i * 8) * 1024 + by + tx] = (bf16_t)tile[tx][ty + i * 8];
  } else if (bid < 6400) {  // ---- ta: [1024][64] -> [64][1024] ----
    int r = bid - 6144, z = r >> 6, r6 = r & 63;
    int bx = (r6 & 1) * 32, by = (r6 >> 1) * 32;
    const float* src = ((z >> 1) ? kta : qta) + (size_t)(z & 1) * 65536;
    bf16_t* dst = ((z >> 1) ? ktaT : qtaT) + (size_t)(z & 1) * 65536;
#pragma unroll
    for (int i = 0; i < 4; ++i)
      tile[ty + i * 8][tx] = src[(size_t)(by + ty + i * 8) * 64 + bx + tx];
    __syncthreads();
#pragma unroll
    for (int i = 0; i < 4; ++i)
      dst[(size_t)(bx + ty + i * 8) * 1024 + by + tx] = (bf16_t)tile[tx][ty + i * 8];
  } else if (bid < 6656) {  // ---- tb: [64][1024] -> [1024][64] ----
    int r = bid - 6400, z = r >> 6, r6 = r & 63;
    int bx = (r6 & 31) * 32, by = (r6 >> 5) * 32;
    const float* src = ((z >> 1) ? ktb : qtb) + (size_t)(z & 1) * 65536;
    bf16_t* dst = ((z >> 1) ? ktbT : qtbT) + (size_t)(z & 1) * 65536;
#pragma unroll
    for (int i = 0; i < 4; ++i)
      tile[ty + i * 8][tx] = src[(size_t)(by + ty + i * 8) * 1024 + bx + tx];
    __syncthreads();
#pragma unroll
    for (int i = 0; i < 4; ++i)
      dst[(size_t)(bx + ty + i * 8) * 64 + by + tx] = (bf16_t)tile[tx][ty + i * 8];
  } else if (bid < 6668) {  // ---- bias concat ----
    int i = (bid - 6656) * 256 + t;
    biasN[i] = (i < 1024) ? bq[i] : (i < 2048 ? bk[i - 1024] : bv[i - 2048]);
  } else {  // ---- low bias: 16 blocks x 16 j-outputs, 16 h-lanes each ----
    int B = bid - 6668;                 // 0..15
    int j = B * 16 + (t >> 4);          // output index 0..255
    int hoff = t & 15;
    const float* b = (j < 128) ? bq : bk;
    const float* ta = ((j < 128) ? qta : kta) + (size_t)((j >> 6) & 1) * 65536;
    int rr = j & 63;
    float s = 0.f;
#pragma unroll 4
    for (int i = 0; i < 64; ++i) {
      int h = hoff + i * 16;
      s += b[h] * ta[(size_t)h * 64 + rr];
    }
    // reduce across the 16 h-lanes (xor widths 1,2,4,8 stay in-wave)
#pragma unroll
    for (int m = 8; m >= 1; m >>= 1) s += __shfl_xor(s, m, 64);
    if (hoff == 0) biasN[3072 + j] = s;
  }
}

// =====================================================================
// 128x128 BK=64 async GEMM core: m97 fragment layout, 64-wide K-steps
// (half the barrier pairs). Bank swizzle via pre-swizzled global SOURCE
// + swizzled read (rule #21), chunk ^= row&7; DMA dest stays linear.
// =====================================================================
template <typename OutT>
static __device__ __forceinline__ void gemm_core_bk64(const bf16_t* __restrict__ A, int lda,
                                                      const bf16_t* __restrict__ Bt, int ldb,
                                                      OutT* __restrict__ C, int ldc,
                                                      const float* __restrict__ bias, int K,
                                                      int bx, int by) {
  __shared__ bf16_t As[128][64];
  __shared__ bf16_t Bs[128][64];
  const int m0 = by * 128, n0 = bx * 128;
  const int t = threadIdx.x, w = t >> 6, lane = t & 63;
  const int wm = (w >> 1) * 64, wn = (w & 1) * 64;
  const int quad = lane >> 4, l16 = lane & 15;
  const int sra = lane >> 3;            // row 0..7 within an 8-row group
  const int sch = lane & 7;             // dest 16B chunk 0..7
  // source col chunk = sch ^ (row&7): LDS[row][q] = global[row][q^(row&7)]
  const bf16_t* Ag = A + (size_t)(m0 + w * 32 + sra) * lda + (sch ^ sra) * 8;
  const bf16_t* Bg = Bt + (size_t)(n0 + w * 32 + sra) * ldb + (sch ^ sra) * 8;
  bf16_t* la = &As[0][0] + w * 2048;    // wave-uniform; lane offset = lane*16B
  bf16_t* lb = &Bs[0][0] + w * 2048;

  f32x4 acc[4][4] = {};
  for (int k0 = 0; k0 < K; k0 += 64) {
    __syncthreads();
#pragma unroll
    for (int c = 0; c < 4; ++c)
      async_cp16(Ag + k0 + (size_t)(c * 8) * lda, la + c * 512);
#pragma unroll
    for (int c = 0; c < 4; ++c)
      async_cp16(Bg + k0 + (size_t)(c * 8) * ldb, lb + c * 512);
    __syncthreads();
#pragma unroll
    for (int ks = 0; ks < 2; ++ks) {
      bf16x8 af[4], bfr[4];
#pragma unroll
      for (int i = 0; i < 4; ++i)
        af[i] = *(const bf16x8*)&As[wm + i * 16 + l16][((ks * 4 + quad) ^ (l16 & 7)) * 8];
#pragma unroll
      for (int j = 0; j < 4; ++j)
        bfr[j] = *(const bf16x8*)&Bs[wn + j * 16 + l16][((ks * 4 + quad) ^ (l16 & 7)) * 8];
#pragma unroll
      for (int i = 0; i < 4; ++i)
#pragma unroll
        for (int j = 0; j < 4; ++j)
          acc[i][j] = __builtin_amdgcn_mfma_f32_16x16x32_bf16(af[i], bfr[j], acc[i][j], 0, 0, 0);
    }
  }
#pragma unroll
  for (int i = 0; i < 4; ++i) {
    int row = m0 + wm + i * 16 + quad * 4;
#pragma unroll
    for (int j = 0; j < 4; ++j) {
      int col = n0 + wn + j * 16 + l16;
      float bv = bias ? bias[col] : 0.f;
#pragma unroll
      for (int r = 0; r < 4; ++r)
        st_out(&C[(size_t)(row + r) * ldc + col], acc[i][j][r] + bv);
    }
  }
}

// 64x128 BK=32 variant (gemm_wta split-K uses it with K=256 chunks)
template <typename OutT>
static __device__ __forceinline__ void gemm_core_async64(const bf16_t* __restrict__ A, int lda,
                                                         const bf16_t* __restrict__ Bt, int ldb,
                                                         OutT* __restrict__ C, int ldc,
                                                         const float* __restrict__ bias, int K,
                                                         int bx, int by) {
  __shared__ bf16_t As[64][32];
  __shared__ bf16_t Bs[128][32];
  const int m0 = by * 64, n0 = bx * 128;
  const int t = threadIdx.x, w = t >> 6, lane = t & 63;
  const int wm = (w >> 1) * 32, wn = (w & 1) * 64;
  const int quad = lane >> 4, l16 = lane & 15;
  const int sra = lane >> 2, sca = (lane & 3) * 8;
  const bf16_t* Ag0 = A + (size_t)(m0 + w * 16 + sra) * lda + sca;
  const bf16_t* Bg0 = Bt + (size_t)(n0 + w * 16 + sra) * ldb + sca;
  const bf16_t* Bg1 = Bt + (size_t)(n0 + 64 + w * 16 + sra) * ldb + sca;
  bf16_t* la0 = &As[0][0] + w * 512;
  bf16_t* lb0 = &Bs[0][0] + w * 512;
  bf16_t* lb1 = &Bs[0][0] + 2048 + w * 512;

  f32x4 acc[2][4] = {};
  for (int k0 = 0; k0 < K; k0 += 32) {
    __syncthreads();
    async_cp16(Ag0 + k0, la0);
    async_cp16(Bg0 + k0, lb0);
    async_cp16(Bg1 + k0, lb1);
    __syncthreads();
    bf16x8 af[2], bfr[4];
#pragma unroll
    for (int i = 0; i < 2; ++i)
      af[i] = *(const bf16x8*)&As[wm + i * 16 + l16][quad * 8];
#pragma unroll
    for (int j = 0; j < 4; ++j)
      bfr[j] = *(const bf16x8*)&Bs[wn + j * 16 + l16][quad * 8];
#pragma unroll
    for (int i = 0; i < 2; ++i)
#pragma unroll
      for (int j = 0; j < 4; ++j)
        acc[i][j] = __builtin_amdgcn_mfma_f32_16x16x32_bf16(af[i], bfr[j], acc[i][j], 0, 0, 0);
  }
#pragma unroll
  for (int i = 0; i < 2; ++i) {
    int row = m0 + wm + i * 16 + quad * 4;
#pragma unroll
    for (int j = 0; j < 4; ++j) {
      int col = n0 + wn + j * 16 + l16;
      float bv = bias ? bias[col] : 0.f;
#pragma unroll
      for (int r = 0; r < 4; ++r)
        st_out(&C[(size_t)(row + r) * ldc + col], acc[i][j][r] + bv);
    }
  }
}

// XCD-aware swizzle (T1): dispatch id d runs on XCD d%8; remap so each
// XCD owns a contiguous tile range. Requires nwg % 8 == 0 (bijective).
__global__ __launch_bounds__(256) void gemm_qkv(const bf16_t* __restrict__ A,
                                                const bf16_t* __restrict__ Bt,
                                                bf16_t* __restrict__ C,
                                                const float* __restrict__ biasN) {
  int id = blockIdx.y * 26 + blockIdx.x;          // 832 = 8 * 104
  int nid = (id & 7) * 104 + (id >> 3);
  gemm_core_bk64<bf16_t>(A, 1024, Bt, 1024, C, 3328, biasN, 1024, nid % 26, nid / 26);
}

__global__ __launch_bounds__(256) void gemm_out(const bf16_t* __restrict__ A,
                                                const bf16_t* __restrict__ Bt,
                                                float* __restrict__ C,
                                                const float* __restrict__ bo) {
  int id = blockIdx.y * 8 + blockIdx.x;           // 256 = 8 * 32
  int nid = (id & 7) * 32 + (id >> 3);
  gemm_core_bk64<float>(A, 1024, Bt, 1024, C, 1024, bo, 1024, nid & 7, nid >> 3);
}

// =====================================================================
// gemm_wta split-K4 (verified R11: part of the -7.4us wta win): 128
// blocks over 4x256 K-chunks, f32 partials in the dead qkv region;
// wta_combine sums + cvt->BtExt before gemm_qkv overwrites the region.
// =====================================================================
__global__ __launch_bounds__(256) void gemm_wta(const bf16_t* __restrict__ qtaT,
                                                const bf16_t* __restrict__ ktaT,
                                                const bf16_t* __restrict__ Wqb,
                                                const bf16_t* __restrict__ Wkb,
                                                float* __restrict__ P) {
  int zz = blockIdx.z;                 // 0..7: z = zz>>2, kc = zz&3
  int z = zz >> 2, kc = zz & 3;
  const bf16_t* A = (z ? ktaT : qtaT) + kc * 256;
  const bf16_t* B = (z ? Wkb : Wqb) + kc * 256;
  gemm_core_async64<float>(A, 1024, B, 1024,
                           P + (size_t)zz * 131072, 1024,
                           nullptr, 256, blockIdx.x, blockIdx.y);
}

__global__ __launch_bounds__(256) void wta_combine(const float* __restrict__ P,
                                                   bf16_t* __restrict__ BtExt) {
  int i = blockIdx.x * 256 + threadIdx.x;   // [0, 262144)
  int z = i >> 17;                          // 0..1
  int off = i & 131071;                     // row*1024 + col, row in [0,128)
  float s = (P[(size_t)(z * 4 + 0) * 131072 + off] + P[(size_t)(z * 4 + 1) * 131072 + off]) +
            (P[(size_t)(z * 4 + 2) * 131072 + off] + P[(size_t)(z * 4 + 3) * 131072 + off]);
  BtExt[(size_t)(3072 + z * 128) * 1024 + off] = (bf16_t)s;
}

// =====================================================================
// fused torsion + q pre-scale by log2(e)/8
// =====================================================================
__global__ __launch_bounds__(256) void lin_torsion_fused(const bf16_t* __restrict__ qtbT,
                                                         const bf16_t* __restrict__ ktbT,
                                                         bf16_t* __restrict__ qkv,
                                                         const float* __restrict__ coupling) {
  __shared__ bf16_t As[128][136];
  __shared__ bf16_t Bs0[128][72];
  __shared__ bf16_t Bs1[128][72];
  const int z = blockIdx.z;
  const bf16_t* Low = qkv + 3072 + z * 128;
  const bf16_t* Tb = z ? ktbT : qtbT;
  bf16_t* X = qkv + z * 1024;

  const int m0 = blockIdx.y * 128, n0 = blockIdx.x * 128;
  const int t = threadIdx.x, w = t >> 6, lane = t & 63;
  const int wm = (w >> 1) * 64, wn = (w & 1) * 64;
  const int quad = lane >> 4, l16 = lane & 15;

  {
    const int sr = t >> 1, sc = (t & 1) * 64;
    const bf16_t* Ag = Low + (size_t)(m0 + sr) * 3328 + sc;
#pragma unroll
    for (int i = 0; i < 8; ++i)
      *(float4*)&As[sr][sc + 8 * i] = *(const float4*)(Ag + 8 * i);
    const int br = t >> 1, bc = (t & 1) * 32;
    const bf16_t* Bg0 = Tb + (size_t)(n0 + br) * 64 + bc;
    const bf16_t* Bg1 = Bg0 + 65536;
#pragma unroll
    for (int i = 0; i < 4; ++i) {
      *(float4*)&Bs0[br][bc + 8 * i] = *(const float4*)(Bg0 + 8 * i);
      *(float4*)&Bs1[br][bc + 8 * i] = *(const float4*)(Bg1 + 8 * i);
    }
  }
  __syncthreads();

  f32x4 acc0[4][4] = {}, acc1[4][4] = {};
#pragma unroll
  for (int ks = 0; ks < 2; ++ks) {
    bf16x8 a0[4], a1[4];
#pragma unroll
    for (int i = 0; i < 4; ++i) {
      a0[i] = *(const bf16x8*)&As[wm + i * 16 + l16][ks * 32 + quad * 8];
      a1[i] = *(const bf16x8*)&As[wm + i * 16 + l16][64 + ks * 32 + quad * 8];
    }
#pragma unroll
    for (int j = 0; j < 4; ++j) {
      bf16x8 b0 = *(const bf16x8*)&Bs0[wn + j * 16 + l16][ks * 32 + quad * 8];
      bf16x8 b1 = *(const bf16x8*)&Bs1[wn + j * 16 + l16][ks * 32 + quad * 8];
#pragma unroll
      for (int i = 0; i < 4; ++i) {
        acc0[i][j] = __builtin_amdgcn_mfma_f32_16x16x32_bf16(a0[i], b0, acc0[i][j], 0, 0, 0);
        acc1[i][j] = __builtin_amdgcn_mfma_f32_16x16x32_bf16(a1[i], b1, acc1[i][j], 0, 0, 0);
      }
    }
  }

  const float PI2 = 6.283185307179586f;
  const float sig = 1.f / (1.f + __expf(-coupling[0]));
  const float scale = z ? 1.f : 0.1803368801111204f;
#pragma unroll
  for (int i = 0; i < 4; ++i) {
#pragma unroll
    for (int j = 0; j < 4; ++j) {
#pragma unroll
      for (int r = 0; r < 4; ++r) {
        int row = m0 + wm + i * 16 + quad * 4 + r;
        int col = n0 + wn + j * 16 + l16;
        size_t idx = (size_t)row * 3328 + col;
        float l1 = acc0[i][j][r], l2 = acc1[i][j][r];
        float corr = __sinf(PI2 * l1) * l1 + __sinf(2.f * PI2 * l2) * l2 * 0.5f;
        X[idx] = (bf16_t)(((float)X[idx] + sig * corr) * scale);
      }
    }
  }
}

// =====================================================================
// Flash attention v18 = EXACT v13 again (scalar-cast softmax). R11's
// cvt_pk inline-asm graft regressed flash 64.4->67.5 us (WRITE 8.2->
// 12.8 MB scratch from asm operand constraints) — falsifier triggered,
// reverted per m240 ("don't hand-write cvt_pk"). v13 = v11 data path +
// counted-vmcnt barrier (T4): 64.4 us, FETCH 69.7 MB, WRITE 8.2 MB.
// =====================================================================
__global__ __launch_bounds__(256, 2) void flash_attn(const bf16_t* __restrict__ qkv,
                                                     bf16_t* __restrict__ aout) {
  constexpr int LD = 3328, SEQ = 2048;
  const int qb = blockIdx.x, bh = blockIdx.y;
  const int b = bh >> 4, h = bh & 15;
  const size_t base = (size_t)b * SEQ * LD + h * 64;
  const bf16_t* Qg = qkv + base;
  const bf16_t* Kg = qkv + base + 1024;
  const bf16_t* Vg = qkv + base + 2048;

  __shared__ __align__(16) unsigned char smem[67584];
  bf16_t(*VT0)[136] = (bf16_t(*)[136])smem;            // V slot 0 (even tiles)
  bf16_t(*VT1)[136] = (bf16_t(*)[136])(smem + 17408);  // V slot 1 (odd tiles)
  bf16_t* Kl0 = (bf16_t*)(smem + 34816);               // K slot 0 [128][64] swz
  bf16_t* Kl1 = (bf16_t*)(smem + 51200);               // K slot 1
  float* LDSo = (float*)smem;                // [256][24] f32, epilogue
  float* Lred = (float*)(smem + 24576);      // [1024] f32, epilogue
  float* invL = (float*)(smem + 28672);      // [128] f32, epilogue

  const int t = threadIdx.x, w = t >> 6, lane = t & 63;
  const int kw = w >> 1, qw = w & 1;
  const int quad = lane >> 4, l16 = lane & 15;
  const int q0 = qb * 128;

  // ---- Q fragments direct from global ----
  bf16x8 qf[4][2];
  {
    const bf16_t* Qrow = Qg + (size_t)(q0 + qw * 64 + l16) * LD + quad * 8;
#pragma unroll
    for (int nf = 0; nf < 4; ++nf)
#pragma unroll
      for (int ks = 0; ks < 2; ++ks)
        qf[nf][ks] = *(const bf16x8*)(Qrow + (size_t)(nf * 16) * LD + ks * 32);
  }

  f32x4 o[4][4] = {};
  float l_part[4] = {0.f, 0.f, 0.f, 0.f};

  const int vg = t >> 3, vcb = (t & 7) * 8;
  // key-slot permutation (PV B-fragment order) ^ 3-bit row-XOR bank swizzle
  const int colb = (((vg >> 3) << 5) | ((vg & 3) << 3) | (((vg >> 2) & 1) << 2)) ^ ((t & 7) << 3);
  const bf16_t* Vbase = Vg + (size_t)(vg * 4) * LD + vcb;

  // K staging geometry: LDS byte o = c*4096 + w*1024 + lane*16 decodes to
  // row = c*32 + w*8 + (lane>>3), stored 16B-chunk = lane&7. Source chunk
  // for that slot = (lane&7) ^ (row&7) = (lane&7) ^ (lane>>3).
  const bf16_t* Kstg = Kg + (size_t)(w * 8 + (lane >> 3)) * LD + ((lane & 7) ^ (lane >> 3)) * 8;

  float4 vr[4];  // V stage regs, one tile in flight (only loop-carried VMEM regs)

  // ---- prologue: DMA K tile 0 into Kl0; stage V tile 0 into VT0;
  //      issue vr loads for tile 1 ----
  {
    bf16_t* dst = Kl0 + w * 512;
#pragma unroll
    for (int c = 0; c < 4; ++c)
      async_cp16(Kstg + (size_t)(c * 32) * LD, dst + c * 2048);
  }
#pragma unroll
  for (int kk = 0; kk < 4; ++kk)
    vr[kk] = *(const float4*)(Vbase + (size_t)kk * LD);
#pragma unroll
  for (int cc = 0; cc < 8; ++cc) {
    union { bf16_t h[4]; uint2 u; } pk;
#pragma unroll
    for (int kk = 0; kk < 4; ++kk) pk.h[kk] = ((const bf16_t*)&vr[kk])[cc];
    *(uint2*)&VT0[vcb + cc][colb] = pk.u;
  }
#pragma unroll
  for (int kk = 0; kk < 4; ++kk)
    vr[kk] = *(const float4*)(Vbase + (size_t)(128 + kk) * LD);
  __syncthreads();  // VT0 + Kl0 ready (vmcnt drained); vr loads in flight

  for (int k0 = 0; k0 < SEQ; k0 += 128) {
    const int cur = (k0 >> 7) & 1;
    bf16_t(*VTc)[136] = cur ? VT1 : VT0;
    bf16_t(*VTn)[136] = cur ? VT0 : VT1;
    const bf16_t* Kc = cur ? Kl1 : Kl0;

    // ---- DMA next K tile into the other slot (completes by next barrier) ----
    if (k0 + 128 < SEQ) {
      bf16_t* dst = (cur ? Kl0 : Kl1) + w * 512;
#pragma unroll
      for (int c = 0; c < 4; ++c)
        async_cp16(Kstg + (size_t)(k0 + 128 + c * 32) * LD, dst + c * 2048);
    }

    // ---- K fragments from LDS (swizzled read; conflict-free) ----
    bf16x8 kf[4][2];
#pragma unroll
    for (int jk = 0; jk < 4; ++jk) {
      int row = kw * 64 + jk * 16 + l16;
#pragma unroll
      for (int ks = 0; ks < 2; ++ks) {
        int ch = (ks * 4 + quad) ^ (l16 & 7);
        kf[jk][ks] = *(const bf16x8*)&Kc[row * 64 + ch * 8];
      }
    }

    // ---- QK^T ----
    f32x4 st[4][4] = {};
    __builtin_amdgcn_s_setprio(1);
#pragma unroll
    for (int ks = 0; ks < 2; ++ks)
#pragma unroll
      for (int jk = 0; jk < 4; ++jk)
#pragma unroll
        for (int nf = 0; nf < 4; ++nf)
          st[jk][nf] = __builtin_amdgcn_mfma_f32_16x16x32_bf16(kf[jk][ks], qf[nf][ks], st[jk][nf], 0, 0, 0);
    __builtin_amdgcn_s_setprio(0);

    // ---- softmax + pack to bf16 (B-fragment key order) ----
    bf16x8 Pp[2][4];
#pragma unroll
    for (int g = 0; g < 2; ++g)
#pragma unroll
      for (int nf = 0; nf < 4; ++nf) {
        union { bf16_t hh[8]; bf16x8 v; } ph;
#pragma unroll
        for (int b2 = 0; b2 < 2; ++b2)
#pragma unroll
          for (int r = 0; r < 4; ++r) {
            float p = exp2f(st[g * 2 + b2][nf][r]);
            l_part[nf] += p;
            ph.hh[b2 * 4 + r] = (bf16_t)p;
          }
        Pp[g][nf] = ph.v;
      }

    // ---- stage: repack vr (tile k0+128) -> VTn, issue V loads k0+256.
    //      ds_writes overlap the PV MFMAs below. ----
    if (k0 + 128 < SEQ) {
#pragma unroll
      for (int cc = 0; cc < 8; ++cc) {
        union { bf16_t h[4]; uint2 u; } pk;
#pragma unroll
        for (int kk = 0; kk < 4; ++kk) pk.h[kk] = ((const bf16_t*)&vr[kk])[cc];
        *(uint2*)&VTn[vcb + cc][colb] = pk.u;
      }
      if (k0 + 256 < SEQ) {
#pragma unroll
        for (int kk = 0; kk < 4; ++kk)
          vr[kk] = *(const float4*)(Vbase + (size_t)(k0 + 256 + kk) * LD);
      }
    }

    // ---- PV from VTc (written last iter; ready since barrier) ----
#pragma unroll
    for (int g = 0; g < 2; ++g) {
      bf16x8 vf[4];
#pragma unroll
      for (int jd = 0; jd < 4; ++jd) {
        int row = jd * 16 + l16;
        int col = (kw * 64 + g * 32 + quad * 8) ^ ((((row >> 3) & 7)) << 3);
        vf[jd] = *(const bf16x8*)&VTc[row][col];
      }
      __builtin_amdgcn_s_setprio(1);
#pragma unroll
      for (int jd = 0; jd < 4; ++jd)
#pragma unroll
        for (int nf = 0; nf < 4; ++nf)
          o[jd][nf] = __builtin_amdgcn_mfma_f32_16x16x32_bf16(vf[jd], Pp[g][nf], o[jd][nf], 0, 0, 0);
      __builtin_amdgcn_s_setprio(0);
    }

    // ---- counted-vmcnt barrier (T4): drain K-DMA (+ repack ds_writes
    // via lgkmcnt) but let the 4 vr loads stay in flight. vr are the 4
    // NEWEST vmem ops this iter (issued after the K-DMA), so vmcnt(4)
    // waits exactly for everything older. Tail iters without vr loads
    // fall back to a full drain so the last K-DMA is covered.
    __builtin_amdgcn_sched_barrier(0);
    if (k0 + 256 < SEQ)
      asm volatile("s_waitcnt vmcnt(4) lgkmcnt(0)" ::: "memory");
    else
      asm volatile("s_waitcnt vmcnt(0) lgkmcnt(0)" ::: "memory");
    __builtin_amdgcn_s_barrier();
    __builtin_amdgcn_sched_barrier(0);
  }

  // ---- epilogue: reduce l and O across kw/quad, divide, store aout ----
#pragma unroll
  for (int nf = 0; nf < 4; ++nf)
    Lred[((kw * 2 + qw) * 4 + quad) * 64 + nf * 16 + l16] = l_part[nf];
  __syncthreads();
  if (t < 128) {
    int qw2 = t >> 6, ql = t & 63;
    float s = 0.f;
#pragma unroll
    for (int kw2 = 0; kw2 < 2; ++kw2)
#pragma unroll
      for (int qd = 0; qd < 4; ++qd)
        s += Lred[((kw2 * 2 + qw2) * 4 + qd) * 64 + ql];
    invL[t] = 1.f / s;
  }
  __syncthreads();

  const int rq = t >> 1, rc0 = (t & 1) * 8;
#pragma unroll
  for (int jd = 0; jd < 4; ++jd) {
#pragma unroll
    for (int nf = 0; nf < 4; ++nf)
      *(f32x4*)&LDSo[(size_t)(kw * 128 + qw * 64 + nf * 16 + l16) * 24 + quad * 4] = o[jd][nf];
    __syncthreads();
    f32x4 a0 = *(const f32x4*)&LDSo[(size_t)rq * 24 + rc0];
    f32x4 a1 = *(const f32x4*)&LDSo[(size_t)(128 + rq) * 24 + rc0];
    f32x4 b0 = *(const f32x4*)&LDSo[(size_t)rq * 24 + rc0 + 4];
    f32x4 b1 = *(const f32x4*)&LDSo[(size_t)(128 + rq) * 24 + rc0 + 4];
    float iv = invL[rq];
    union { bf16_t h[8]; uint4 u; } pk;
#pragma unroll
    for (int r = 0; r < 4; ++r) {
      pk.h[r] = (bf16_t)((a0[r] + a1[r]) * iv);
      pk.h[4 + r] = (bf16_t)((b0[r] + b1[r]) * iv);
    }
    *(uint4*)&aout[(size_t)(b * SEQ + q0 + rq) * 1024 + h * 64 + jd * 16 + rc0] = pk.u;
    if (jd < 3) __syncthreads();
  }
}

// =====================================================================
// host launch
// =====================================================================
extern "C" void kernel_launch(void* const* d_in, const int* in_sizes, int n_in,
                              void* d_out, int out_size, void* d_ws, size_t ws_size,
                              hipStream_t stream) {
  const float* hs   = (const float*)d_in[0];
  const float* Wq   = (const float*)d_in[1];
  const float* bq   = (const float*)d_in[2];
  const float* Wk   = (const float*)d_in[3];
  const float* bk   = (const float*)d_in[4];
  const float* Wv   = (const float*)d_in[5];
  const float* bv   = (const float*)d_in[6];
  const float* Wo   = (const float*)d_in[7];
  const float* bo   = (const float*)d_in[8];
  const float* qta  = (const float*)d_in[9];
  const float* qtb  = (const float*)d_in[10];
  const float* kta  = (const float*)d_in[11];
  const float* ktb  = (const float*)d_in[12];
  const float* coup = (const float*)d_in[13];
  float* out = (float*)d_out;

  uint8_t* ws = (uint8_t*)d_ws;
  bf16_t* hsb   = (bf16_t*)(ws);              // dead after gemm_qkv -> aout
  bf16_t* aout  = (bf16_t*)(ws);              // flash output overlays hsb
  bf16_t* BtExt = (bf16_t*)(ws + 8388608);    // [3328][1024]
  bf16_t* WoT   = (bf16_t*)(ws + 16777216);   // 2 MB
  float*  biasN = (float*)(ws + 18874368);    // 16 KB
  bf16_t* qkv   = (bf16_t*)(ws + 18890752);   // [4096][3328] 27.3 MB
  float*  wtaP  = (float*)(ws + 18890752);    // 4 MB wta partials; dead
                                              // before gemm_qkv writes qkv
  bf16_t* Wqb   = (bf16_t*)(ws + 46153728);   // prep scratch
  bf16_t* Wkb   = (bf16_t*)(ws + 48250880);
  bf16_t* qtaT  = (bf16_t*)(ws + 50348032);
  bf16_t* ktaT  = (bf16_t*)(ws + 50610176);
  bf16_t* qtbT  = (bf16_t*)(ws + 50872320);
  bf16_t* ktbT  = (bf16_t*)(ws + 51134464);

  dim3 b256(256);

  prep<<<6684, b256, 0, stream>>>(hs, hsb, Wq, Wk, Wv, Wo, BtExt, WoT, Wqb, Wkb,
                                  qta, kta, qtaT, ktaT, qtb, ktb, qtbT, ktbT,
                                  bq, bk, bv, biasN);
  gemm_wta<<<dim3(8, 2, 8), b256, 0, stream>>>(qtaT, ktaT, Wqb, Wkb, wtaP);
  wta_combine<<<1024, b256, 0, stream>>>(wtaP, BtExt);
  gemm_qkv<<<dim3(26, 32), b256, 0, stream>>>(hsb, BtExt, qkv, biasN);
  lin_torsion_fused<<<dim3(8, 32, 2), b256, 0, stream>>>(qtbT, ktbT, qkv, coup);
  flash_attn<<<dim3(16, 32), b256, 0, stream>>>(qkv, aout);
  gemm_out<<<dim3(8, 32), b256, 0, stream>>>(aout, WoT, out, bo);
}

// Round 13
// 251.965 us; speedup vs baseline: 1.1917x; 1.0079x over previous
//
#include <hip/hip_runtime.h>
#include <hip/hip_bf16.h>
#include <cstdint>
#include <cstddef>

typedef __bf16 bf16_t;
typedef __bf16 bf16x8 __attribute__((ext_vector_type(8)));
typedef float f32x4 __attribute__((ext_vector_type(4)));

static __device__ __forceinline__ void st_out(float* p, float v) { *p = v; }
static __device__ __forceinline__ void st_out(bf16_t* p, float v) { *p = (bf16_t)v; }

static __device__ __forceinline__ void async_cp16(const bf16_t* g, bf16_t* l) {
  __builtin_amdgcn_global_load_lds(
      (const __attribute__((address_space(1))) void*)g,
      (__attribute__((address_space(3))) void*)l, 16, 0, 0);
}

// =====================================================================
// prep: all setup work in ONE launch. 1D grid, block ranges:
// [0,2048) cvt hs | [2048,3072) W transposes (64x64 reg-transpose)
// [3072,3328) ta^T | [3328,3584) tb^T | [3584,3596) bias concat
// [3596,3612) low bias
// W-transpose rewrite (R13): old path was 32x32 LDS tiles with 2-byte
// scalar stores (G13 violation) + barrier. New: 64x64 tiles, 4x4 block
// per thread held in registers -- 4 coalesced float4 loads (lane-fast
// on columns), register transpose, 4 packed uint2 (4xbf16) stores +
// packed passthrough for Wqb/Wkb. No LDS, no barrier, 1024 blocks.
// =====================================================================
__global__ __launch_bounds__(256) void prep(const float* __restrict__ hs, bf16_t* __restrict__ hsb,
                                            const float* __restrict__ Wq, const float* __restrict__ Wk,
                                            const float* __restrict__ Wv, const float* __restrict__ Wo,
                                            bf16_t* __restrict__ BtExt, bf16_t* __restrict__ WoT,
                                            bf16_t* __restrict__ Wqb, bf16_t* __restrict__ Wkb,
                                            const float* __restrict__ qta, const float* __restrict__ kta,
                                            bf16_t* __restrict__ qtaT, bf16_t* __restrict__ ktaT,
                                            const float* __restrict__ qtb, const float* __restrict__ ktb,
                                            bf16_t* __restrict__ qtbT, bf16_t* __restrict__ ktbT,
                                            const float* __restrict__ bq, const float* __restrict__ bk,
                                            const float* __restrict__ bv, float* __restrict__ biasN) {
  __shared__ float tile[32][33];
  const int bid = blockIdx.x, t = threadIdx.x;
  const int tx = t & 31, ty = t >> 5;

  if (bid < 2048) {  // ---- cvt ----
    int i = (bid * 256 + t) * 8;
    float4 a = *(const float4*)(hs + i);
    float4 b = *(const float4*)(hs + i + 4);
    union { bf16_t h[8]; uint4 u; } p;
    p.h[0] = (bf16_t)a.x; p.h[1] = (bf16_t)a.y; p.h[2] = (bf16_t)a.z; p.h[3] = (bf16_t)a.w;
    p.h[4] = (bf16_t)b.x; p.h[5] = (bf16_t)b.y; p.h[6] = (bf16_t)b.z; p.h[7] = (bf16_t)b.w;
    *(uint4*)(hsb + i) = p.u;
  } else if (bid < 3072) {  // ---- W transposes: 64x64 reg-transpose ----
    int r = bid - 2048, z = r >> 8, r8 = r & 255;
    int bx = (r8 & 15) * 64, by = (r8 >> 4) * 64;
    const float* src = z == 0 ? Wq : z == 1 ? Wk : z == 2 ? Wv : Wo;
    bf16_t* dst = z == 3 ? WoT : BtExt + (size_t)z * 1048576;
    bf16_t* sd = z == 0 ? Wqb : z == 1 ? Wkb : nullptr;
    const int lx = t & 15, ly = t >> 4;   // lx lane-fast: load columns
    float4 v[4];
#pragma unroll
    for (int r2 = 0; r2 < 4; ++r2)
      v[r2] = *(const float4*)(src + (size_t)(by + ly * 4 + r2) * 1024 + bx + lx * 4);
    if (sd) {
#pragma unroll
      for (int r2 = 0; r2 < 4; ++r2) {
        union { bf16_t h[4]; uint2 u; } pk;
        pk.h[0] = (bf16_t)v[r2].x; pk.h[1] = (bf16_t)v[r2].y;
        pk.h[2] = (bf16_t)v[r2].z; pk.h[3] = (bf16_t)v[r2].w;
        *(uint2*)(sd + (size_t)(by + ly * 4 + r2) * 1024 + bx + lx * 4) = pk.u;
      }
    }
    const float* vv = (const float*)v;    // v[r2] component j = vv[r2*4+j]
#pragma unroll
    for (int j = 0; j < 4; ++j) {
      union { bf16_t h[4]; uint2 u; } pk;
      pk.h[0] = (bf16_t)vv[0 * 4 + j];
      pk.h[1] = (bf16_t)vv[1 * 4 + j];
      pk.h[2] = (bf16_t)vv[2 * 4 + j];
      pk.h[3] = (bf16_t)vv[3 * 4 + j];
      // dst[bx+4lx+j][by+4ly .. +3] = src[by+4ly..+3][bx+4lx+j]
      *(uint2*)(dst + (size_t)(bx + lx * 4 + j) * 1024 + by + ly * 4) = pk.u;
    }
  } else if (bid < 3328) {  // ---- ta: [1024][64] -> [64][1024] ----
    int r = bid - 3072, z = r >> 6, r6 = r & 63;
    int bx = (r6 & 1) * 32, by = (r6 >> 1) * 32;
    const float* src = ((z >> 1) ? kta : qta) + (size_t)(z & 1) * 65536;
    bf16_t* dst = ((z >> 1) ? ktaT : qtaT) + (size_t)(z & 1) * 65536;
#pragma unroll
    for (int i = 0; i < 4; ++i)
      tile[ty + i * 8][tx] = src[(size_t)(by + ty + i * 8) * 64 + bx + tx];
    __syncthreads();
#pragma unroll
    for (int i = 0; i < 4; ++i)
      dst[(size_t)(bx + ty + i * 8) * 1024 + by + tx] = (bf16_t)tile[tx][ty + i * 8];
  } else if (bid < 3584) {  // ---- tb: [64][1024] -> [1024][64] ----
    int r = bid - 3328, z = r >> 6, r6 = r & 63;
    int bx = (r6 & 31) * 32, by = (r6 >> 5) * 32;
    const float* src = ((z >> 1) ? ktb : qtb) + (size_t)(z & 1) * 65536;
    bf16_t* dst = ((z >> 1) ? ktbT : qtbT) + (size_t)(z & 1) * 65536;
#pragma unroll
    for (int i = 0; i < 4; ++i)
      tile[ty + i * 8][tx] = src[(size_t)(by + ty + i * 8) * 1024 + bx + tx];
    __syncthreads();
#pragma unroll
    for (int i = 0; i < 4; ++i)
      dst[(size_t)(bx + ty + i * 8) * 64 + by + tx] = (bf16_t)tile[tx][ty + i * 8];
  } else if (bid < 3596) {  // ---- bias concat ----
    int i = (bid - 3584) * 256 + t;
    biasN[i] = (i < 1024) ? bq[i] : (i < 2048 ? bk[i - 1024] : bv[i - 2048]);
  } else {  // ---- low bias: 16 blocks x 16 j-outputs, 16 h-lanes each ----
    int B = bid - 3596;                 // 0..15
    int j = B * 16 + (t >> 4);          // output index 0..255
    int hoff = t & 15;
    const float* b = (j < 128) ? bq : bk;
    const float* ta = ((j < 128) ? qta : kta) + (size_t)((j >> 6) & 1) * 65536;
    int rr = j & 63;
    float s = 0.f;
#pragma unroll 4
    for (int i = 0; i < 64; ++i) {
      int h = hoff + i * 16;
      s += b[h] * ta[(size_t)h * 64 + rr];
    }
    // reduce across the 16 h-lanes (xor widths 1,2,4,8 stay in-wave)
#pragma unroll
    for (int m = 8; m >= 1; m >>= 1) s += __shfl_xor(s, m, 64);
    if (hoff == 0) biasN[3072 + j] = s;
  }
}

// =====================================================================
// 128x128 BK=64 async GEMM core: m97 fragment layout, 64-wide K-steps
// (half the barrier pairs). Bank swizzle via pre-swizzled global SOURCE
// + swizzled read (rule #21), chunk ^= row&7; DMA dest stays linear.
// =====================================================================
template <typename OutT>
static __device__ __forceinline__ void gemm_core_bk64(const bf16_t* __restrict__ A, int lda,
                                                      const bf16_t* __restrict__ Bt, int ldb,
                                                      OutT* __restrict__ C, int ldc,
                                                      const float* __restrict__ bias, int K,
                                                      int bx, int by) {
  __shared__ bf16_t As[128][64];
  __shared__ bf16_t Bs[128][64];
  const int m0 = by * 128, n0 = bx * 128;
  const int t = threadIdx.x, w = t >> 6, lane = t & 63;
  const int wm = (w >> 1) * 64, wn = (w & 1) * 64;
  const int quad = lane >> 4, l16 = lane & 15;
  const int sra = lane >> 3;            // row 0..7 within an 8-row group
  const int sch = lane & 7;             // dest 16B chunk 0..7
  // source col chunk = sch ^ (row&7): LDS[row][q] = global[row][q^(row&7)]
  const bf16_t* Ag = A + (size_t)(m0 + w * 32 + sra) * lda + (sch ^ sra) * 8;
  const bf16_t* Bg = Bt + (size_t)(n0 + w * 32 + sra) * ldb + (sch ^ sra) * 8;
  bf16_t* la = &As[0][0] + w * 2048;    // wave-uniform; lane offset = lane*16B
  bf16_t* lb = &Bs[0][0] + w * 2048;

  f32x4 acc[4][4] = {};
  for (int k0 = 0; k0 < K; k0 += 64) {
    __syncthreads();
#pragma unroll
    for (int c = 0; c < 4; ++c)
      async_cp16(Ag + k0 + (size_t)(c * 8) * lda, la + c * 512);
#pragma unroll
    for (int c = 0; c < 4; ++c)
      async_cp16(Bg + k0 + (size_t)(c * 8) * ldb, lb + c * 512);
    __syncthreads();
#pragma unroll
    for (int ks = 0; ks < 2; ++ks) {
      bf16x8 af[4], bfr[4];
#pragma unroll
      for (int i = 0; i < 4; ++i)
        af[i] = *(const bf16x8*)&As[wm + i * 16 + l16][((ks * 4 + quad) ^ (l16 & 7)) * 8];
#pragma unroll
      for (int j = 0; j < 4; ++j)
        bfr[j] = *(const bf16x8*)&Bs[wn + j * 16 + l16][((ks * 4 + quad) ^ (l16 & 7)) * 8];
#pragma unroll
      for (int i = 0; i < 4; ++i)
#pragma unroll
        for (int j = 0; j < 4; ++j)
          acc[i][j] = __builtin_amdgcn_mfma_f32_16x16x32_bf16(af[i], bfr[j], acc[i][j], 0, 0, 0);
    }
  }
#pragma unroll
  for (int i = 0; i < 4; ++i) {
    int row = m0 + wm + i * 16 + quad * 4;
#pragma unroll
    for (int j = 0; j < 4; ++j) {
      int col = n0 + wn + j * 16 + l16;
      float bv = bias ? bias[col] : 0.f;
#pragma unroll
      for (int r = 0; r < 4; ++r)
        st_out(&C[(size_t)(row + r) * ldc + col], acc[i][j][r] + bv);
    }
  }
}

// 64x128 BK=32 variant (gemm_wta split-K uses it with K=256 chunks)
template <typename OutT>
static __device__ __forceinline__ void gemm_core_async64(const bf16_t* __restrict__ A, int lda,
                                                         const bf16_t* __restrict__ Bt, int ldb,
                                                         OutT* __restrict__ C, int ldc,
                                                         const float* __restrict__ bias, int K,
                                                         int bx, int by) {
  __shared__ bf16_t As[64][32];
  __shared__ bf16_t Bs[128][32];
  const int m0 = by * 64, n0 = bx * 128;
  const int t = threadIdx.x, w = t >> 6, lane = t & 63;
  const int wm = (w >> 1) * 32, wn = (w & 1) * 64;
  const int quad = lane >> 4, l16 = lane & 15;
  const int sra = lane >> 2, sca = (lane & 3) * 8;
  const bf16_t* Ag0 = A + (size_t)(m0 + w * 16 + sra) * lda + sca;
  const bf16_t* Bg0 = Bt + (size_t)(n0 + w * 16 + sra) * ldb + sca;
  const bf16_t* Bg1 = Bt + (size_t)(n0 + 64 + w * 16 + sra) * ldb + sca;
  bf16_t* la0 = &As[0][0] + w * 512;
  bf16_t* lb0 = &Bs[0][0] + w * 512;
  bf16_t* lb1 = &Bs[0][0] + 2048 + w * 512;

  f32x4 acc[2][4] = {};
  for (int k0 = 0; k0 < K; k0 += 32) {
    __syncthreads();
    async_cp16(Ag0 + k0, la0);
    async_cp16(Bg0 + k0, lb0);
    async_cp16(Bg1 + k0, lb1);
    __syncthreads();
    bf16x8 af[2], bfr[4];
#pragma unroll
    for (int i = 0; i < 2; ++i)
      af[i] = *(const bf16x8*)&As[wm + i * 16 + l16][quad * 8];
#pragma unroll
    for (int j = 0; j < 4; ++j)
      bfr[j] = *(const bf16x8*)&Bs[wn + j * 16 + l16][quad * 8];
#pragma unroll
    for (int i = 0; i < 2; ++i)
#pragma unroll
      for (int j = 0; j < 4; ++j)
        acc[i][j] = __builtin_amdgcn_mfma_f32_16x16x32_bf16(af[i], bfr[j], acc[i][j], 0, 0, 0);
  }
#pragma unroll
  for (int i = 0; i < 2; ++i) {
    int row = m0 + wm + i * 16 + quad * 4;
#pragma unroll
    for (int j = 0; j < 4; ++j) {
      int col = n0 + wn + j * 16 + l16;
      float bv = bias ? bias[col] : 0.f;
#pragma unroll
      for (int r = 0; r < 4; ++r)
        st_out(&C[(size_t)(row + r) * ldc + col], acc[i][j][r] + bv);
    }
  }
}

// XCD-aware swizzle (T1): dispatch id d runs on XCD d%8; remap so each
// XCD owns a contiguous tile range. Requires nwg % 8 == 0 (bijective).
__global__ __launch_bounds__(256) void gemm_qkv(const bf16_t* __restrict__ A,
                                                const bf16_t* __restrict__ Bt,
                                                bf16_t* __restrict__ C,
                                                const float* __restrict__ biasN) {
  int id = blockIdx.y * 26 + blockIdx.x;          // 832 = 8 * 104
  int nid = (id & 7) * 104 + (id >> 3);
  gemm_core_bk64<bf16_t>(A, 1024, Bt, 1024, C, 3328, biasN, 1024, nid % 26, nid / 26);
}

__global__ __launch_bounds__(256) void gemm_out(const bf16_t* __restrict__ A,
                                                const bf16_t* __restrict__ Bt,
                                                float* __restrict__ C,
                                                const float* __restrict__ bo) {
  int id = blockIdx.y * 8 + blockIdx.x;           // 256 = 8 * 32
  int nid = (id & 7) * 32 + (id >> 3);
  gemm_core_bk64<float>(A, 1024, Bt, 1024, C, 1024, bo, 1024, nid & 7, nid >> 3);
}

// =====================================================================
// gemm_wta split-K4 (verified R11/R12): 128 blocks over 4x256 K-chunks,
// f32 partials in the dead qkv region; wta_combine sums + cvt->BtExt
// before gemm_qkv overwrites the region.
// =====================================================================
__global__ __launch_bounds__(256) void gemm_wta(const bf16_t* __restrict__ qtaT,
                                                const bf16_t* __restrict__ ktaT,
                                                const bf16_t* __restrict__ Wqb,
                                                const bf16_t* __restrict__ Wkb,
                                                float* __restrict__ P) {
  int zz = blockIdx.z;                 // 0..7: z = zz>>2, kc = zz&3
  int z = zz >> 2, kc = zz & 3;
  const bf16_t* A = (z ? ktaT : qtaT) + kc * 256;
  const bf16_t* B = (z ? Wkb : Wqb) + kc * 256;
  gemm_core_async64<float>(A, 1024, B, 1024,
                           P + (size_t)zz * 131072, 1024,
                           nullptr, 256, blockIdx.x, blockIdx.y);
}

__global__ __launch_bounds__(256) void wta_combine(const float* __restrict__ P,
                                                   bf16_t* __restrict__ BtExt) {
  int i = blockIdx.x * 256 + threadIdx.x;   // [0, 262144)
  int z = i >> 17;                          // 0..1
  int off = i & 131071;                     // row*1024 + col, row in [0,128)
  float s = (P[(size_t)(z * 4 + 0) * 131072 + off] + P[(size_t)(z * 4 + 1) * 131072 + off]) +
            (P[(size_t)(z * 4 + 2) * 131072 + off] + P[(size_t)(z * 4 + 3) * 131072 + off]);
  BtExt[(size_t)(3072 + z * 128) * 1024 + off] = (bf16_t)s;
}

// =====================================================================
// fused torsion + q pre-scale by log2(e)/8
// =====================================================================
__global__ __launch_bounds__(256) void lin_torsion_fused(const bf16_t* __restrict__ qtbT,
                                                         const bf16_t* __restrict__ ktbT,
                                                         bf16_t* __restrict__ qkv,
                                                         const float* __restrict__ coupling) {
  __shared__ bf16_t As[128][136];
  __shared__ bf16_t Bs0[128][72];
  __shared__ bf16_t Bs1[128][72];
  const int z = blockIdx.z;
  const bf16_t* Low = qkv + 3072 + z * 128;
  const bf16_t* Tb = z ? ktbT : qtbT;
  bf16_t* X = qkv + z * 1024;

  const int m0 = blockIdx.y * 128, n0 = blockIdx.x * 128;
  const int t = threadIdx.x, w = t >> 6, lane = t & 63;
  const int wm = (w >> 1) * 64, wn = (w & 1) * 64;
  const int quad = lane >> 4, l16 = lane & 15;

  {
    const int sr = t >> 1, sc = (t & 1) * 64;
    const bf16_t* Ag = Low + (size_t)(m0 + sr) * 3328 + sc;
#pragma unroll
    for (int i = 0; i < 8; ++i)
      *(float4*)&As[sr][sc + 8 * i] = *(const float4*)(Ag + 8 * i);
    const int br = t >> 1, bc = (t & 1) * 32;
    const bf16_t* Bg0 = Tb + (size_t)(n0 + br) * 64 + bc;
    const bf16_t* Bg1 = Bg0 + 65536;
#pragma unroll
    for (int i = 0; i < 4; ++i) {
      *(float4*)&Bs0[br][bc + 8 * i] = *(const float4*)(Bg0 + 8 * i);
      *(float4*)&Bs1[br][bc + 8 * i] = *(const float4*)(Bg1 + 8 * i);
    }
  }
  __syncthreads();

  f32x4 acc0[4][4] = {}, acc1[4][4] = {};
#pragma unroll
  for (int ks = 0; ks < 2; ++ks) {
    bf16x8 a0[4], a1[4];
#pragma unroll
    for (int i = 0; i < 4; ++i) {
      a0[i] = *(const bf16x8*)&As[wm + i * 16 + l16][ks * 32 + quad * 8];
      a1[i] = *(const bf16x8*)&As[wm + i * 16 + l16][64 + ks * 32 + quad * 8];
    }
#pragma unroll
    for (int j = 0; j < 4; ++j) {
      bf16x8 b0 = *(const bf16x8*)&Bs0[wn + j * 16 + l16][ks * 32 + quad * 8];
      bf16x8 b1 = *(const bf16x8*)&Bs1[wn + j * 16 + l16][ks * 32 + quad * 8];
#pragma unroll
      for (int i = 0; i < 4; ++i) {
        acc0[i][j] = __builtin_amdgcn_mfma_f32_16x16x32_bf16(a0[i], b0, acc0[i][j], 0, 0, 0);
        acc1[i][j] = __builtin_amdgcn_mfma_f32_16x16x32_bf16(a1[i], b1, acc1[i][j], 0, 0, 0);
      }
    }
  }

  const float PI2 = 6.283185307179586f;
  const float sig = 1.f / (1.f + __expf(-coupling[0]));
  const float scale = z ? 1.f : 0.1803368801111204f;
#pragma unroll
  for (int i = 0; i < 4; ++i) {
#pragma unroll
    for (int j = 0; j < 4; ++j) {
#pragma unroll
      for (int r = 0; r < 4; ++r) {
        int row = m0 + wm + i * 16 + quad * 4 + r;
        int col = n0 + wn + j * 16 + l16;
        size_t idx = (size_t)row * 3328 + col;
        float l1 = acc0[i][j][r], l2 = acc1[i][j][r];
        float corr = __sinf(PI2 * l1) * l1 + __sinf(2.f * PI2 * l2) * l2 * 0.5f;
        X[idx] = (bf16_t)(((float)X[idx] + sig * corr) * scale);
      }
    }
  }
}

// =====================================================================
// Flash attention v13 (frozen since R12: 64.3 us, FETCH 69.7 MB, WRITE
// 8.2 MB, absmax 2.6e-4). v11 data path + counted-vmcnt barrier (T4).
// =====================================================================
__global__ __launch_bounds__(256, 2) void flash_attn(const bf16_t* __restrict__ qkv,
                                                     bf16_t* __restrict__ aout) {
  constexpr int LD = 3328, SEQ = 2048;
  const int qb = blockIdx.x, bh = blockIdx.y;
  const int b = bh >> 4, h = bh & 15;
  const size_t base = (size_t)b * SEQ * LD + h * 64;
  const bf16_t* Qg = qkv + base;
  const bf16_t* Kg = qkv + base + 1024;
  const bf16_t* Vg = qkv + base + 2048;

  __shared__ __align__(16) unsigned char smem[67584];
  bf16_t(*VT0)[136] = (bf16_t(*)[136])smem;            // V slot 0 (even tiles)
  bf16_t(*VT1)[136] = (bf16_t(*)[136])(smem + 17408);  // V slot 1 (odd tiles)
  bf16_t* Kl0 = (bf16_t*)(smem + 34816);               // K slot 0 [128][64] swz
  bf16_t* Kl1 = (bf16_t*)(smem + 51200);               // K slot 1
  float* LDSo = (float*)smem;                // [256][24] f32, epilogue
  float* Lred = (float*)(smem + 24576);      // [1024] f32, epilogue
  float* invL = (float*)(smem + 28672);      // [128] f32, epilogue

  const int t = threadIdx.x, w = t >> 6, lane = t & 63;
  const int kw = w >> 1, qw = w & 1;
  const int quad = lane >> 4, l16 = lane & 15;
  const int q0 = qb * 128;

  // ---- Q fragments direct from global ----
  bf16x8 qf[4][2];
  {
    const bf16_t* Qrow = Qg + (size_t)(q0 + qw * 64 + l16) * LD + quad * 8;
#pragma unroll
    for (int nf = 0; nf < 4; ++nf)
#pragma unroll
      for (int ks = 0; ks < 2; ++ks)
        qf[nf][ks] = *(const bf16x8*)(Qrow + (size_t)(nf * 16) * LD + ks * 32);
  }

  f32x4 o[4][4] = {};
  float l_part[4] = {0.f, 0.f, 0.f, 0.f};

  const int vg = t >> 3, vcb = (t & 7) * 8;
  // key-slot permutation (PV B-fragment order) ^ 3-bit row-XOR bank swizzle
  const int colb = (((vg >> 3) << 5) | ((vg & 3) << 3) | (((vg >> 2) & 1) << 2)) ^ ((t & 7) << 3);
  const bf16_t* Vbase = Vg + (size_t)(vg * 4) * LD + vcb;

  // K staging geometry: LDS byte o = c*4096 + w*1024 + lane*16 decodes to
  // row = c*32 + w*8 + (lane>>3), stored 16B-chunk = lane&7. Source chunk
  // for that slot = (lane&7) ^ (row&7) = (lane&7) ^ (lane>>3).
  const bf16_t* Kstg = Kg + (size_t)(w * 8 + (lane >> 3)) * LD + ((lane & 7) ^ (lane >> 3)) * 8;

  float4 vr[4];  // V stage regs, one tile in flight (only loop-carried VMEM regs)

  // ---- prologue: DMA K tile 0 into Kl0; stage V tile 0 into VT0;
  //      issue vr loads for tile 1 ----
  {
    bf16_t* dst = Kl0 + w * 512;
#pragma unroll
    for (int c = 0; c < 4; ++c)
      async_cp16(Kstg + (size_t)(c * 32) * LD, dst + c * 2048);
  }
#pragma unroll
  for (int kk = 0; kk < 4; ++kk)
    vr[kk] = *(const float4*)(Vbase + (size_t)kk * LD);
#pragma unroll
  for (int cc = 0; cc < 8; ++cc) {
    union { bf16_t h[4]; uint2 u; } pk;
#pragma unroll
    for (int kk = 0; kk < 4; ++kk) pk.h[kk] = ((const bf16_t*)&vr[kk])[cc];
    *(uint2*)&VT0[vcb + cc][colb] = pk.u;
  }
#pragma unroll
  for (int kk = 0; kk < 4; ++kk)
    vr[kk] = *(const float4*)(Vbase + (size_t)(128 + kk) * LD);
  __syncthreads();  // VT0 + Kl0 ready (vmcnt drained); vr loads in flight

  for (int k0 = 0; k0 < SEQ; k0 += 128) {
    const int cur = (k0 >> 7) & 1;
    bf16_t(*VTc)[136] = cur ? VT1 : VT0;
    bf16_t(*VTn)[136] = cur ? VT0 : VT1;
    const bf16_t* Kc = cur ? Kl1 : Kl0;

    // ---- DMA next K tile into the other slot (completes by next barrier) ----
    if (k0 + 128 < SEQ) {
      bf16_t* dst = (cur ? Kl0 : Kl1) + w * 512;
#pragma unroll
      for (int c = 0; c < 4; ++c)
        async_cp16(Kstg + (size_t)(k0 + 128 + c * 32) * LD, dst + c * 2048);
    }

    // ---- K fragments from LDS (swizzled read; conflict-free) ----
    bf16x8 kf[4][2];
#pragma unroll
    for (int jk = 0; jk < 4; ++jk) {
      int row = kw * 64 + jk * 16 + l16;
#pragma unroll
      for (int ks = 0; ks < 2; ++ks) {
        int ch = (ks * 4 + quad) ^ (l16 & 7);
        kf[jk][ks] = *(const bf16x8*)&Kc[row * 64 + ch * 8];
      }
    }

    // ---- QK^T ----
    f32x4 st[4][4] = {};
    __builtin_amdgcn_s_setprio(1);
#pragma unroll
    for (int ks = 0; ks < 2; ++ks)
#pragma unroll
      for (int jk = 0; jk < 4; ++jk)
#pragma unroll
        for (int nf = 0; nf < 4; ++nf)
          st[jk][nf] = __builtin_amdgcn_mfma_f32_16x16x32_bf16(kf[jk][ks], qf[nf][ks], st[jk][nf], 0, 0, 0);
    __builtin_amdgcn_s_setprio(0);

    // ---- softmax + pack to bf16 (B-fragment key order) ----
    bf16x8 Pp[2][4];
#pragma unroll
    for (int g = 0; g < 2; ++g)
#pragma unroll
      for (int nf = 0; nf < 4; ++nf) {
        union { bf16_t hh[8]; bf16x8 v; } ph;
#pragma unroll
        for (int b2 = 0; b2 < 2; ++b2)
#pragma unroll
          for (int r = 0; r < 4; ++r) {
            float p = exp2f(st[g * 2 + b2][nf][r]);
            l_part[nf] += p;
            ph.hh[b2 * 4 + r] = (bf16_t)p;
          }
        Pp[g][nf] = ph.v;
      }

    // ---- stage: repack vr (tile k0+128) -> VTn, issue V loads k0+256.
    //      ds_writes overlap the PV MFMAs below. ----
    if (k0 + 128 < SEQ) {
#pragma unroll
      for (int cc = 0; cc < 8; ++cc) {
        union { bf16_t h[4]; uint2 u; } pk;
#pragma unroll
        for (int kk = 0; kk < 4; ++kk) pk.h[kk] = ((const bf16_t*)&vr[kk])[cc];
        *(uint2*)&VTn[vcb + cc][colb] = pk.u;
      }
      if (k0 + 256 < SEQ) {
#pragma unroll
        for (int kk = 0; kk < 4; ++kk)
          vr[kk] = *(const float4*)(Vbase + (size_t)(k0 + 256 + kk) * LD);
      }
    }

    // ---- PV from VTc (written last iter; ready since barrier) ----
#pragma unroll
    for (int g = 0; g < 2; ++g) {
      bf16x8 vf[4];
#pragma unroll
      for (int jd = 0; jd < 4; ++jd) {
        int row = jd * 16 + l16;
        int col = (kw * 64 + g * 32 + quad * 8) ^ ((((row >> 3) & 7)) << 3);
        vf[jd] = *(const bf16x8*)&VTc[row][col];
      }
      __builtin_amdgcn_s_setprio(1);
#pragma unroll
      for (int jd = 0; jd < 4; ++jd)
#pragma unroll
        for (int nf = 0; nf < 4; ++nf)
          o[jd][nf] = __builtin_amdgcn_mfma_f32_16x16x32_bf16(vf[jd], Pp[g][nf], o[jd][nf], 0, 0, 0);
      __builtin_amdgcn_s_setprio(0);
    }

    // ---- counted-vmcnt barrier (T4): drain K-DMA (+ repack ds_writes
    // via lgkmcnt) but let the 4 vr loads stay in flight. vr are the 4
    // NEWEST vmem ops this iter (issued after the K-DMA), so vmcnt(4)
    // waits exactly for everything older. Tail iters without vr loads
    // fall back to a full drain so the last K-DMA is covered.
    __builtin_amdgcn_sched_barrier(0);
    if (k0 + 256 < SEQ)
      asm volatile("s_waitcnt vmcnt(4) lgkmcnt(0)" ::: "memory");
    else
      asm volatile("s_waitcnt vmcnt(0) lgkmcnt(0)" ::: "memory");
    __builtin_amdgcn_s_barrier();
    __builtin_amdgcn_sched_barrier(0);
  }

  // ---- epilogue: reduce l and O across kw/quad, divide, store aout ----
#pragma unroll
  for (int nf = 0; nf < 4; ++nf)
    Lred[((kw * 2 + qw) * 4 + quad) * 64 + nf * 16 + l16] = l_part[nf];
  __syncthreads();
  if (t < 128) {
    int qw2 = t >> 6, ql = t & 63;
    float s = 0.f;
#pragma unroll
    for (int kw2 = 0; kw2 < 2; ++kw2)
#pragma unroll
      for (int qd = 0; qd < 4; ++qd)
        s += Lred[((kw2 * 2 + qw2) * 4 + qd) * 64 + ql];
    invL[t] = 1.f / s;
  }
  __syncthreads();

  const int rq = t >> 1, rc0 = (t & 1) * 8;
#pragma unroll
  for (int jd = 0; jd < 4; ++jd) {
#pragma unroll
    for (int nf = 0; nf < 4; ++nf)
      *(f32x4*)&LDSo[(size_t)(kw * 128 + qw * 64 + nf * 16 + l16) * 24 + quad * 4] = o[jd][nf];
    __syncthreads();
    f32x4 a0 = *(const f32x4*)&LDSo[(size_t)rq * 24 + rc0];
    f32x4 a1 = *(const f32x4*)&LDSo[(size_t)(128 + rq) * 24 + rc0];
    f32x4 b0 = *(const f32x4*)&LDSo[(size_t)rq * 24 + rc0 + 4];
    f32x4 b1 = *(const f32x4*)&LDSo[(size_t)(128 + rq) * 24 + rc0 + 4];
    float iv = invL[rq];
    union { bf16_t h[8]; uint4 u; } pk;
#pragma unroll
    for (int r = 0; r < 4; ++r) {
      pk.h[r] = (bf16_t)((a0[r] + a1[r]) * iv);
      pk.h[4 + r] = (bf16_t)((b0[r] + b1[r]) * iv);
    }
    *(uint4*)&aout[(size_t)(b * SEQ + q0 + rq) * 1024 + h * 64 + jd * 16 + rc0] = pk.u;
    if (jd < 3) __syncthreads();
  }
}

// =====================================================================
// host launch
// =====================================================================
extern "C" void kernel_launch(void* const* d_in, const int* in_sizes, int n_in,
                              void* d_out, int out_size, void* d_ws, size_t ws_size,
                              hipStream_t stream) {
  const float* hs   = (const float*)d_in[0];
  const float* Wq   = (const float*)d_in[1];
  const float* bq   = (const float*)d_in[2];
  const float* Wk   = (const float*)d_in[3];
  const float* bk   = (const float*)d_in[4];
  const float* Wv   = (const float*)d_in[5];
  const float* bv   = (const float*)d_in[6];
  const float* Wo   = (const float*)d_in[7];
  const float* bo   = (const float*)d_in[8];
  const float* qta  = (const float*)d_in[9];
  const float* qtb  = (const float*)d_in[10];
  const float* kta  = (const float*)d_in[11];
  const float* ktb  = (const float*)d_in[12];
  const float* coup = (const float*)d_in[13];
  float* out = (float*)d_out;

  uint8_t* ws = (uint8_t*)d_ws;
  bf16_t* hsb   = (bf16_t*)(ws);              // dead after gemm_qkv -> aout
  bf16_t* aout  = (bf16_t*)(ws);              // flash output overlays hsb
  bf16_t* BtExt = (bf16_t*)(ws + 8388608);    // [3328][1024]
  bf16_t* WoT   = (bf16_t*)(ws + 16777216);   // 2 MB
  float*  biasN = (float*)(ws + 18874368);    // 16 KB
  bf16_t* qkv   = (bf16_t*)(ws + 18890752);   // [4096][3328] 27.3 MB
  float*  wtaP  = (float*)(ws + 18890752);    // 4 MB wta partials; dead
                                              // before gemm_qkv writes qkv
  bf16_t* Wqb   = (bf16_t*)(ws + 46153728);   // prep scratch
  bf16_t* Wkb   = (bf16_t*)(ws + 48250880);
  bf16_t* qtaT  = (bf16_t*)(ws + 50348032);
  bf16_t* ktaT  = (bf16_t*)(ws + 50610176);
  bf16_t* qtbT  = (bf16_t*)(ws + 50872320);
  bf16_t* ktbT  = (bf16_t*)(ws + 51134464);

  dim3 b256(256);

  prep<<<3612, b256, 0, stream>>>(hs, hsb, Wq, Wk, Wv, Wo, BtExt, WoT, Wqb, Wkb,
                                  qta, kta, qtaT, ktaT, qtb, ktb, qtbT, ktbT,
                                  bq, bk, bv, biasN);
  gemm_wta<<<dim3(8, 2, 8), b256, 0, stream>>>(qtaT, ktaT, Wqb, Wkb, wtaP);
  wta_combine<<<1024, b256, 0, stream>>>(wtaP, BtExt);
  gemm_qkv<<<dim3(26, 32), b256, 0, stream>>>(hsb, BtExt, qkv, biasN);
  lin_torsion_fused<<<dim3(8, 32, 2), b256, 0, stream>>>(qtbT, ktbT, qkv, coup);
  flash_attn<<<dim3(16, 32), b256, 0, stream>>>(qkv, aout);
  gemm_out<<<dim3(8, 32), b256, 0, stream>>>(aout, WoT, out, bo);
}